// Round 13
// baseline (1975.918 us; speedup 1.0000x reference)
//
#include <hip/hip_runtime.h>

typedef __attribute__((ext_vector_type(4))) float f32x4;
typedef __attribute__((ext_vector_type(8))) short bf16x8;
typedef __attribute__((ext_vector_type(4))) unsigned u32x4;

#define T_DIM 128
#define B_DIM 32
#define H_DIM 1024
#define V_DIM 32000
#define MROWS 4096    // T*B
#define NBLK 64       // persistent recurrence blocks
#define PUBSTEP 32768 // dwords per slot in tagged pub buffer
#define WSTRIDE 1028  // LDS W row stride (ushorts): bank step 2 -> conflict-free

__device__ __forceinline__ ushort f2bf(float f){
  union { float f; unsigned u; } x; x.f = f;
  unsigned u = x.u;
  unsigned r = (u + 0x7fffu + ((u >> 16) & 1u)) >> 16;
  return (ushort)r;
}
__device__ __forceinline__ float bf2f(ushort h){
  union { unsigned u; float f; } x; x.u = ((unsigned)h) << 16;
  return x.f;
}

__device__ __forceinline__ void async_copy16(void* lds, const void* g){
  __builtin_amdgcn_global_load_lds((const __attribute__((address_space(1))) void*)g,
                                   (__attribute__((address_space(3))) void*)lds, 16, 0, 0);
}

// ---------------- casts ----------------
__global__ void cast_bf16_kernel(const float* __restrict__ s, ushort* __restrict__ d, int n4){
  int stride = gridDim.x * blockDim.x;
  for (int i = blockIdx.x*blockDim.x + threadIdx.x; i < n4; i += stride){
    float4 v = ((const float4*)s)[i];
    ushort4 o = make_ushort4(f2bf(v.x), f2bf(v.y), f2bf(v.z), f2bf(v.w));
    ((ushort4*)d)[i] = o;
  }
}

__global__ void cast_split_kernel(const float* __restrict__ s, ushort* __restrict__ dh,
                                  ushort* __restrict__ dl, int n4){
  int stride = gridDim.x * blockDim.x;
  for (int i = blockIdx.x*blockDim.x + threadIdx.x; i < n4; i += stride){
    float4 v = ((const float4*)s)[i];
    ushort4 h = make_ushort4(f2bf(v.x), f2bf(v.y), f2bf(v.z), f2bf(v.w));
    ushort4 l = make_ushort4(f2bf(v.x - bf2f(h.x)), f2bf(v.y - bf2f(h.y)),
                             f2bf(v.z - bf2f(h.z)), f2bf(v.w - bf2f(h.w)));
    ((ushort4*)dh)[i] = h;
    ((ushort4*)dl)[i] = l;
  }
}

// ---------------- plain m97-style bf16 GEMM (for ixfx) ----------------
__global__ __launch_bounds__(256) void gemm_bt_plain(
    const ushort* __restrict__ A, const ushort* __restrict__ B,
    float* __restrict__ C, int N, int K, int NTN)
{
  __shared__ ushort lA[128*32];
  __shared__ ushort lB[128*32];
  int tid = threadIdx.x;
  int lane = tid & 63, wid = tid >> 6;
  int tm = blockIdx.x / NTN, tn = blockIdx.x % NTN;
  int row0 = tm << 7, col0 = tn << 7;

  f32x4 acc[4][4] = {};

  auto stage = [&](const ushort* __restrict__ g, ushort* l, int r0, int k0){
    int c = wid << 1;
    const ushort* s0 = g + (size_t)(r0 + (c<<4) + (lane>>2))*K + k0 + ((lane&3)<<3);
    async_copy16(l + (c<<9), s0);
    async_copy16(l + ((c+1)<<9), s0 + (size_t)16*K);
  };

  int nk = K >> 5;
  stage(A, lA, row0, 0);
  stage(B, lB, col0, 0);
  int wm = (wid >> 1) << 6, wn = (wid & 1) << 6;
  int kg = (lane >> 4) << 3;
  int ar = lane & 15;

  for (int kt = 0; kt < nk; ++kt){
    __syncthreads();
    bf16x8 af[4], bfr[4];
    #pragma unroll
    for (int mi = 0; mi < 4; ++mi) af[mi]  = *(const bf16x8*)&lA[(wm + mi*16 + ar)*32 + kg];
    #pragma unroll
    for (int ni = 0; ni < 4; ++ni) bfr[ni] = *(const bf16x8*)&lB[(wn + ni*16 + ar)*32 + kg];
    #pragma unroll
    for (int mi = 0; mi < 4; ++mi)
      #pragma unroll
      for (int ni = 0; ni < 4; ++ni)
        acc[mi][ni] = __builtin_amdgcn_mfma_f32_16x16x32_bf16(af[mi], bfr[ni], acc[mi][ni], 0, 0, 0);
    if (kt + 1 < nk){
      __syncthreads();
      stage(A, lA, row0, (kt+1) << 5);
      stage(B, lB, col0, (kt+1) << 5);
    }
  }

  int rr = (lane >> 4) << 2;
  #pragma unroll
  for (int mi = 0; mi < 4; ++mi)
    #pragma unroll
    for (int ni = 0; ni < 4; ++ni){
      int r  = row0 + wm + mi*16 + rr;
      int cc = col0 + wn + ni*16 + ar;
      #pragma unroll
      for (int q = 0; q < 4; ++q)
        C[(size_t)(r + q) * N + cc] = acc[mi][ni][q];
    }
}

// ---------------- Vproj: 256x256, BK=64, 8-phase interleave (m201-style) ----------------
// C[4096][32000] = A(cstate chunked)[4096][1024] * B[32000][1024]^T + bias + LSE partials.
// A chunked: row r -> t=r>>5, m=r&31; elem = t*32768 + (k>>4)*512 + m*16 + (k&15).
// 2 dbuf x (A[256][64] + B[256][64]); half-tiles by row-bit (A: bit6, B: bit5) = 16 KB
// = 2 loads/thread. Quad order per tile: (fr0,fc0),(fr0,fc1),(fr1,fc1),(fr1,fc0).
// Stage 8 half-tiles/iter into just-freed regions; vmcnt(4) gates at ph4/ph8 only.
// 8-slot XOR swizzle phys = conc ^ (row&7): linear LDS dest, pre-swizzled global src.
__global__ __launch_bounds__(512) void gemm256(
    const ushort* __restrict__ A, const ushort* __restrict__ B,
    float* __restrict__ C, const float* __restrict__ bias,
    float* __restrict__ pmax, float* __restrict__ psum)
{
  __shared__ ushort lA[2][256*64];
  __shared__ ushort lB[2][256*64];
  __shared__ float redm[2][4][128], reds[2][4][128];

  const int K = 1024, N = V_DIM, NTN = 125;
  int tid = threadIdx.x, lane = tid & 63, wid = tid >> 6;
  int wm = wid >> 2, wn = wid & 3;
  int bid = blockIdx.x;
  int xcd = bid & 7, id = bid >> 3;       // 2000 blocks: 250 per XCD
  int tm = (xcd << 1) | (id & 1);         // 2 M-bands per XCD
  int tn = id >> 1;                       // 125 N-tiles
  int row0 = tm << 8, col0 = tn << 8;
  int ar = lane & 15, kgi = lane >> 4;

  f32x4 acc[8][4] = {};
  bf16x8 a_[8], b_[4];

#define SBAR __builtin_amdgcn_sched_barrier(0)
#define BAR  __builtin_amdgcn_s_barrier()

#define STG_A(buf, kt, h) do { \
  _Pragma("unroll") \
  for (int j_ = 0; j_ < 2; ++j_){ \
    int idx_ = j_*512 + tid; \
    int rih_ = idx_ >> 3, ps_ = idx_ & 7; \
    int row_ = ((rih_ >> 6) << 7) | ((h) << 6) | (rih_ & 63); \
    int g_ = ps_ ^ (row_ & 7); \
    int kc_ = ((kt) << 6) + (g_ << 3); \
    int rA_ = row0 + row_; \
    const ushort* s_ = A + ((size_t)(rA_>>5)<<15) + ((size_t)(kc_>>4)<<9) + ((rA_&31)<<4) + (kc_&15); \
    async_copy16(&lA[buf][row_*64 + ps_*8], s_); \
  } } while(0)

#define STG_B(buf, kt, h) do { \
  _Pragma("unroll") \
  for (int j_ = 0; j_ < 2; ++j_){ \
    int idx_ = j_*512 + tid; \
    int rih_ = idx_ >> 3, ps_ = idx_ & 7; \
    int row_ = ((rih_ >> 5) << 6) | ((h) << 5) | (rih_ & 31); \
    int g_ = ps_ ^ (row_ & 7); \
    int kc_ = ((kt) << 6) + (g_ << 3); \
    const ushort* s_ = B + (size_t)(col0 + row_)*K + kc_; \
    async_copy16(&lB[buf][row_*64 + ps_*8], s_); \
  } } while(0)

#define QREAD(bsel, FRH, FCH) do { \
  _Pragma("unroll") \
  for (int f_ = 0; f_ < 4; ++f_) \
    _Pragma("unroll") \
    for (int kk_ = 0; kk_ < 2; ++kk_){ \
      int row_ = wm*128 + ((FRH)*4 + f_)*16 + ar; \
      int conc_ = kk_*4 + kgi; \
      a_[f_*2+kk_] = *(const bf16x8*)&lA[bsel][row_*64 + ((conc_ ^ (row_&7))<<3)]; \
    } \
  _Pragma("unroll") \
  for (int f_ = 0; f_ < 2; ++f_) \
    _Pragma("unroll") \
    for (int kk_ = 0; kk_ < 2; ++kk_){ \
      int row_ = wn*64 + ((FCH)*2 + f_)*16 + ar; \
      int conc_ = kk_*4 + kgi; \
      b_[f_*2+kk_] = *(const bf16x8*)&lB[bsel][row_*64 + ((conc_ ^ (row_&7))<<3)]; \
    } } while(0)

#define QMFMA(FRH, FCH) do { \
  __builtin_amdgcn_s_setprio(1); \
  _Pragma("unroll") \
  for (int f_ = 0; f_ < 4; ++f_) \
    _Pragma("unroll") \
    for (int c_ = 0; c_ < 2; ++c_) \
      _Pragma("unroll") \
      for (int kk_ = 0; kk_ < 2; ++kk_) \
        acc[(FRH)*4+f_][(FCH)*2+c_] = __builtin_amdgcn_mfma_f32_16x16x32_bf16( \
            a_[f_*2+kk_], b_[c_*2+kk_], acc[(FRH)*4+f_][(FCH)*2+c_], 0, 0, 0); \
  __builtin_amdgcn_s_setprio(0); \
} while(0)

#define VM4 asm volatile("s_waitcnt vmcnt(4)" ::: "memory")
#define VM0 asm volatile("s_waitcnt vmcnt(0)" ::: "memory")

  // prologue: tile0 full + tile1 A_lo,B_hi; wait tile0 landed (4 left in flight)
  STG_A(0,0,0); STG_B(0,0,0); STG_A(0,0,1); STG_B(0,0,1);
  STG_A(1,1,0); STG_B(1,1,1);
  VM4;
  SBAR; BAR; SBAR;

  for (int it = 0; it < 8; ++it){
    int kO = 2*it + 1, kE2 = 2*it + 2, kO2 = 2*it + 3;
    // ph1: E quad(0,0) | stage O.A_hi, O.B_lo -> buf1
    QREAD(0, 0, 0);
    STG_A(1, kO, 1); STG_B(1, kO, 0);
    SBAR; BAR; QMFMA(0, 0); SBAR; BAR; SBAR;
    // ph2: E quad(0,1)
    QREAD(0, 0, 1);
    SBAR; BAR; QMFMA(0, 1); SBAR; BAR; SBAR;
    // ph3: E quad(1,1) | stage E2.A_lo -> buf0
    QREAD(0, 1, 1);
    if (it < 7) STG_A(0, kE2, 0);
    SBAR; BAR; QMFMA(1, 1); SBAR; BAR; SBAR;
    // ph4: E quad(1,0) | stage E2.B_hi; GATE
    QREAD(0, 1, 0);
    if (it < 7){ STG_B(0, kE2, 1); VM4; } else { VM0; }
    SBAR; BAR; QMFMA(1, 0); SBAR; BAR; SBAR;
    // ph5: O quad(0,0) | stage E2.A_hi + E2.B_lo
    QREAD(1, 0, 0);
    if (it < 7){ STG_A(0, kE2, 1); STG_B(0, kE2, 0); }
    SBAR; BAR; QMFMA(0, 0); SBAR; BAR; SBAR;
    // ph6: O quad(0,1)
    QREAD(1, 0, 1);
    SBAR; BAR; QMFMA(0, 1); SBAR; BAR; SBAR;
    // ph7: O quad(1,1) | stage O2.A_lo -> buf1
    QREAD(1, 1, 1);
    if (it < 7) STG_A(1, kO2, 0);
    SBAR; BAR; QMFMA(1, 1); SBAR; BAR; SBAR;
    // ph8: O quad(1,0) | stage O2.B_hi; GATE
    QREAD(1, 1, 0);
    if (it < 7){ STG_B(1, kO2, 1); VM4; }
    SBAR; BAR; QMFMA(1, 0); SBAR; BAR; SBAR;
  }

#undef SBAR
#undef BAR
#undef STG_A
#undef STG_B
#undef QREAD
#undef QMFMA
#undef VM4
#undef VM0

  // epilogue: bias + C-write + per-(row, tile) LSE partials
  float bb4[4];
  #pragma unroll
  for (int fc = 0; fc < 4; ++fc) bb4[fc] = bias[col0 + wn*64 + fc*16 + ar];
  #pragma unroll
  for (int fr = 0; fr < 8; ++fr){
    #pragma unroll
    for (int q = 0; q < 4; ++q){
      int rl = fr*16 + (lane>>4)*4 + q;
      int r = row0 + wm*128 + rl;
      float vals[4];
      #pragma unroll
      for (int fc = 0; fc < 4; ++fc){
        vals[fc] = acc[fr][fc][q] + bb4[fc];
        C[(size_t)r * N + col0 + wn*64 + fc*16 + ar] = vals[fc];
      }
      float m = fmaxf(fmaxf(vals[0], vals[1]), fmaxf(vals[2], vals[3]));
      #pragma unroll
      for (int o = 1; o < 16; o <<= 1) m = fmaxf(m, __shfl_xor(m, o));
      float s = expf(vals[0]-m) + expf(vals[1]-m) + expf(vals[2]-m) + expf(vals[3]-m);
      #pragma unroll
      for (int o = 1; o < 16; o <<= 1) s += __shfl_xor(s, o);
      if (ar == 0){ redm[wm][wn][rl] = m; reds[wm][wn][rl] = s; }
    }
  }
  __syncthreads();
  if (tid < 256){
    int wm2 = tid >> 7, rl = tid & 127;
    float m0 = redm[wm2][0][rl], m1 = redm[wm2][1][rl];
    float m2 = redm[wm2][2][rl], m3 = redm[wm2][3][rl];
    float M = fmaxf(fmaxf(m0, m1), fmaxf(m2, m3));
    float S = reds[wm2][0][rl]*expf(m0-M) + reds[wm2][1][rl]*expf(m1-M)
            + reds[wm2][2][rl]*expf(m2-M) + reds[wm2][3][rl]*expf(m3-M);
    int r = row0 + wm2*128 + rl;
    pmax[(size_t)r*NTN + tn] = M;
    psum[(size_t)r*NTN + tn] = S;
  }
}

// ---------------- persistent recurrence: tagged dataflow + untagged dual-store ----------------
__global__ __launch_bounds__(512) void ran_all(
    unsigned* __restrict__ pub, ushort* __restrict__ cst,
    const float* __restrict__ hiddenf,
    const ushort* __restrict__ wh, const ushort* __restrict__ wl,
    const float* __restrict__ b_i, const float* __restrict__ b_f,
    const float* __restrict__ ixfx, const float* __restrict__ x_all,
    float* __restrict__ hid_final)
{
  __shared__ ushort lWh[32*WSTRIDE];
  __shared__ ushort lWl[32*WSTRIDE];
  __shared__ f32x4 part[4][2][2][64];   // [kq][mh][gate][lane]
  __shared__ float gsm[2*32*17];
  __shared__ float cfl[32][17];

  int tid = threadIdx.x, lane = tid & 63, wid = tid >> 6;
  int kq = wid & 3, mh = wid >> 2;           // MFMA roles
  int rgate = wid & 1, rmh = (wid >> 1) & 1; // reduce roles (wid<4)
  int bid = blockIdx.x;
  int nb = bid << 4;
  int ar = lane & 15, kg = (lane >> 4) << 3;
  int um = tid >> 4, uk = tid & 15;

  #pragma unroll
  for (int u = 0; u < 8; ++u){
    int unit = u*512 + tid;
    int r = unit >> 7, off = (unit & 127) << 3;
    int g = r >> 4, c = r & 15;
    size_t gsrc = (size_t)((g<<10) + nb + c) * H_DIM + off;
    *(bf16x8*)&lWh[r*WSTRIDE + off] = *(const bf16x8*)&wh[gsrc];
    *(bf16x8*)&lWl[r*WSTRIDE + off] = *(const bf16x8*)&wl[gsrc];
  }
  cfl[um][uk] = hiddenf[(um<<10) + nb + uk];
  float bb = (rgate ? b_f : b_i)[nb + ar];
  const ushort* b0h = &lWh[(     ar)*WSTRIDE + (kq<<8) + kg];
  const ushort* b0l = &lWl[(     ar)*WSTRIDE + (kq<<8) + kg];
  const ushort* b1h = &lWh[(16 + ar)*WSTRIDE + (kq<<8) + kg];
  const ushort* b1l = &lWl[(16 + ar)*WSTRIDE + (kq<<8) + kg];
  int abase = (kq<<13) + ((kg>>4)<<9) + (((mh<<4) + ar)<<4) + (kg & 8);
  __syncthreads();

  for (int t = 0; t < T_DIM; ++t){
    float xq1 = x_all[((size_t)t<<15) + (um<<10) + nb + uk];
    float pix[4];
    if (wid < 4){
      const float* ix_t = ixfx + ((size_t)t<<16);
      #pragma unroll
      for (int q = 0; q < 4; ++q){
        int m = (rmh<<4) + ((lane>>4)<<2) + q;
        pix[q] = ix_t[m*2048 + (rgate<<10) + nb + ar];
      }
    }

    const unsigned* ps = pub + ((size_t)t << 15) + abase;
    unsigned expt = (unsigned)(t + 1) << 16;
    u32x4 w0[8], w1[8];
    int tries = 0;
    while (1){
      #pragma unroll
      for (int f = 0; f < 8; ++f){
        const unsigned* p = ps + (f << 10);
        asm volatile("global_load_dwordx4 %0, %2, off sc0 sc1\n\t"
                     "global_load_dwordx4 %1, %2, off offset:16 sc0 sc1"
                     : "=&v"(w0[f]), "=&v"(w1[f]) : "v"(p));
      }
      asm volatile("s_waitcnt vmcnt(0)" ::: "memory");
      __builtin_amdgcn_sched_barrier(0);
      unsigned bad = 0;
      #pragma unroll
      for (int f = 0; f < 8; ++f){
        bad |= (w0[f][0]^expt)|(w0[f][1]^expt)|(w0[f][2]^expt)|(w0[f][3]^expt)
             | (w1[f][0]^expt)|(w1[f][1]^expt)|(w1[f][2]^expt)|(w1[f][3]^expt);
      }
      if (__ballot((bad & 0xFFFF0000u) != 0) == 0ull) break;
      if (++tries > (1<<15)) break;   // bounded: fail fast, not hang
    }

    f32x4 g0h = {}, g0l = {}, g1h = {}, g1l = {};
    #pragma unroll
    for (int f = 0; f < 8; ++f){
      union { unsigned u[4]; bf16x8 v; } cv;
      cv.u[0] = (w0[f][0] & 0xFFFFu) | (w0[f][1] << 16);
      cv.u[1] = (w0[f][2] & 0xFFFFu) | (w0[f][3] << 16);
      cv.u[2] = (w1[f][0] & 0xFFFFu) | (w1[f][1] << 16);
      cv.u[3] = (w1[f][2] & 0xFFFFu) | (w1[f][3] << 16);
      int ob = f << 5;
      bf16x8 v0h = *(const bf16x8*)&b0h[ob];
      bf16x8 v0l = *(const bf16x8*)&b0l[ob];
      bf16x8 v1h = *(const bf16x8*)&b1h[ob];
      bf16x8 v1l = *(const bf16x8*)&b1l[ob];
      g0h = __builtin_amdgcn_mfma_f32_16x16x32_bf16(cv.v, v0h, g0h, 0, 0, 0);
      g0l = __builtin_amdgcn_mfma_f32_16x16x32_bf16(cv.v, v0l, g0l, 0, 0, 0);
      g1h = __builtin_amdgcn_mfma_f32_16x16x32_bf16(cv.v, v1h, g1h, 0, 0, 0);
      g1l = __builtin_amdgcn_mfma_f32_16x16x32_bf16(cv.v, v1l, g1l, 0, 0, 0);
    }
    part[kq][mh][0][lane] = g0h + g0l;
    part[kq][mh][1][lane] = g1h + g1l;
    __syncthreads();

    if (wid < 4){
      f32x4 sum = part[0][rmh][rgate][lane] + part[1][rmh][rgate][lane]
                + part[2][rmh][rgate][lane] + part[3][rmh][rgate][lane];
      #pragma unroll
      for (int q = 0; q < 4; ++q){
        int m = (rmh<<4) + ((lane>>4)<<2) + q;
        float pre = sum[q] + bb + pix[q];
        gsm[((rgate<<5) + m)*17 + ar] = 1.f / (1.f + expf(-pre));
      }
    }
    __syncthreads();

    {
      float iv = gsm[um*17 + uk];
      float fv = gsm[(32+um)*17 + uk];
      float cv2 = cfl[um][uk];
      float cn = iv * xq1 + fv * cv2;
      cfl[um][uk] = cn;
      ushort hb = f2bf(cn);
      unsigned word = ((unsigned)(t + 2) << 16) | (unsigned)hb;
      __hip_atomic_store(&pub[((size_t)(t+1) << 15) + (bid << 9) + tid], word,
                         __ATOMIC_RELAXED, __HIP_MEMORY_SCOPE_AGENT);
      cst[((size_t)t << 15) + (bid << 9) + tid] = hb;  // untagged copy for gemm256 (plain store)
      if (t == T_DIM-1) hid_final[(um<<10) + nb + uk] = cn;
    }
    __syncthreads();
  }
}

// init: write tagged c_init into pub slot 0 (tag = 1)
__global__ void init_c_kernel(const float* __restrict__ hidden, unsigned* __restrict__ pub){
  int i = blockIdx.x * blockDim.x + threadIdx.x;   // 0..32767
  float v = hidden[i];
  int m = i >> 10, col = i & 1023;
  pub[((col>>4)<<9) + (m<<4) + (col&15)] = (1u << 16) | (unsigned)f2bf(v);
}

// ---------------- fused lse + subtract: one block per row ----------------
__global__ __launch_bounds__(256) void subf_kernel(float* __restrict__ logits,
                                                   const float* __restrict__ pmax,
                                                   const float* __restrict__ psum){
  __shared__ float sl;
  size_t row = blockIdx.x;
  int tid = threadIdx.x;
  if (tid < 64){
    float m = -1e30f, s = 0.f;
    for (int i = tid; i < 125; i += 64){
      float mi = pmax[row*125 + i], si = psum[row*125 + i];
      float M = fmaxf(m, mi);
      s = s*expf(m - M) + si*expf(mi - M);
      m = M;
    }
    #pragma unroll
    for (int o = 32; o; o >>= 1){
      float m2 = __shfl_xor(m, o), s2 = __shfl_xor(s, o);
      float M = fmaxf(m, m2);
      s = s*expf(m - M) + s2*expf(m2 - M);
      m = M;
    }
    if (tid == 0) sl = m + logf(s);
  }
  __syncthreads();
  float l = sl;
  float4* p4 = (float4*)(logits + row * (size_t)V_DIM);
  for (int i = tid; i < V_DIM/4; i += 256){
    float4 v = p4[i];
    v.x -= l; v.y -= l; v.z -= l; v.w -= l;
    p4[i] = v;
  }
}

// ---------------- launch ----------------
extern "C" void kernel_launch(void* const* d_in, const int* in_sizes, int n_in,
                              void* d_out, int out_size, void* d_ws, size_t ws_size,
                              hipStream_t stream)
{
  const float* input  = (const float*)d_in[0];
  const float* hidden = (const float*)d_in[1];
  const float* w_ic   = (const float*)d_in[2];
  const float* w_ix   = (const float*)d_in[3];
  const float* w_fc   = (const float*)d_in[4];
  const float* w_fx   = (const float*)d_in[5];
  const float* b_i    = (const float*)d_in[6];
  const float* b_f    = (const float*)d_in[7];
  const float* W_out  = (const float*)d_in[8];
  const float* b_out  = (const float*)d_in[9];
  float* out = (float*)d_out;

  char* ws = (char*)d_ws;
  ushort* wout_bf = (ushort*)(ws + 0);          // 0 .. 65,536,000
  ushort* in_hi   = (ushort*)(ws + 65536000);   // 8,388,608 (dead after ixfx gemm)
  ushort* wx      = (ushort*)(ws + 73924608);   // [w_ix; w_fx] plain bf16, 4,194,304
  ushort* wc_hi   = (ushort*)(ws + 90701824);   // split W for recurrence
  ushort* wc_lo   = (ushort*)(ws + 94896128);
  // overlays (regions dead at time of use):
  unsigned* pub   = (unsigned*)(ws + 65536000); // [129][32768] tagged c, 16,908,288 B
  ushort* cstate  = (ushort*)(ws + 82444288);   // [128][32768] bf16; tail 131KB overlaps wc_hi
                                                //   but is only written at t>=126 (W-LDS copies
                                                //   provably done by then via dataflow)
  float*  pmax    = (float*)(ws + 94896128);    // [4096][125] over wc_lo (dead post-ran_all)
  float*  psum    = (float*)(ws + 99090432);
  float*  ixfx    = out;                        // [4096][2048] scratch in logits region

  cast_bf16_kernel<<<2048,256,0,stream>>>(W_out, wout_bf, V_DIM*H_DIM/4);
  cast_bf16_kernel<<<1024,256,0,stream>>>(input, in_hi, MROWS*H_DIM/4);
  cast_bf16_kernel<<<256,256,0,stream>>>(w_ix, wx,             H_DIM*H_DIM/4);
  cast_bf16_kernel<<<256,256,0,stream>>>(w_fx, wx+H_DIM*H_DIM, H_DIM*H_DIM/4);
  cast_split_kernel<<<256,256,0,stream>>>(w_ic, wc_hi,             wc_lo,             H_DIM*H_DIM/4);
  cast_split_kernel<<<256,256,0,stream>>>(w_fc, wc_hi+H_DIM*H_DIM, wc_lo+H_DIM*H_DIM, H_DIM*H_DIM/4);

  // ixfx = input @ [w_ix; w_fx]^T (plain bf16) — before pub overlays in_hi/wx
  gemm_bt_plain<<<32*16,256,0,stream>>>(in_hi, wx, ixfx, 2048, H_DIM, 16);

  // clear tags (graph-replay safety), seed slot 0
  hipMemsetAsync(pub, 0, (size_t)129 * PUBSTEP * 4, stream);
  init_c_kernel<<<128,256,0,stream>>>(hidden, pub);

  ran_all<<<NBLK,512,0,stream>>>(pub, cstate, hidden, wc_hi, wc_lo, b_i, b_f,
                                 ixfx, input, out + (size_t)MROWS*V_DIM);

  // 8-phase 256^2 logits GEMM + fused LSE partials (reads cstate directly)
  gemm256<<<2000,512,0,stream>>>(cstate, wout_bf, out, b_out, pmax, psum);
  subf_kernel<<<MROWS,256,0,stream>>>(out, pmax, psum);
}

// Round 14
// 1943.857 us; speedup vs baseline: 1.0165x; 1.0165x over previous
//
#include <hip/hip_runtime.h>

typedef __attribute__((ext_vector_type(4))) float f32x4;
typedef __attribute__((ext_vector_type(8))) short bf16x8;
typedef __attribute__((ext_vector_type(4))) unsigned u32x4;

#define T_DIM 128
#define B_DIM 32
#define H_DIM 1024
#define V_DIM 32000
#define MROWS 4096    // T*B
#define NBLK 64       // persistent recurrence blocks
#define PUBSTEP 32768 // dwords per slot in tagged pub buffer
#define WSTRIDE 1028  // LDS W row stride (ushorts): bank step 2 -> conflict-free
#define GBK 32        // gemm256 K-tile

__device__ __forceinline__ ushort f2bf(float f){
  union { float f; unsigned u; } x; x.f = f;
  unsigned u = x.u;
  unsigned r = (u + 0x7fffu + ((u >> 16) & 1u)) >> 16;
  return (ushort)r;
}
__device__ __forceinline__ float bf2f(ushort h){
  union { unsigned u; float f; } x; x.u = ((unsigned)h) << 16;
  return x.f;
}

__device__ __forceinline__ void async_copy16(void* lds, const void* g){
  __builtin_amdgcn_global_load_lds((const __attribute__((address_space(1))) void*)g,
                                   (__attribute__((address_space(3))) void*)lds, 16, 0, 0);
}

// ---------------- casts ----------------
__global__ void cast_bf16_kernel(const float* __restrict__ s, ushort* __restrict__ d, int n4){
  int stride = gridDim.x * blockDim.x;
  for (int i = blockIdx.x*blockDim.x + threadIdx.x; i < n4; i += stride){
    float4 v = ((const float4*)s)[i];
    ushort4 o = make_ushort4(f2bf(v.x), f2bf(v.y), f2bf(v.z), f2bf(v.w));
    ((ushort4*)d)[i] = o;
  }
}

__global__ void cast_split_kernel(const float* __restrict__ s, ushort* __restrict__ dh,
                                  ushort* __restrict__ dl, int n4){
  int stride = gridDim.x * blockDim.x;
  for (int i = blockIdx.x*blockDim.x + threadIdx.x; i < n4; i += stride){
    float4 v = ((const float4*)s)[i];
    ushort4 h = make_ushort4(f2bf(v.x), f2bf(v.y), f2bf(v.z), f2bf(v.w));
    ushort4 l = make_ushort4(f2bf(v.x - bf2f(h.x)), f2bf(v.y - bf2f(h.y)),
                             f2bf(v.z - bf2f(h.z)), f2bf(v.w - bf2f(h.w)));
    ((ushort4*)dh)[i] = h;
    ((ushort4*)dl)[i] = l;
  }
}

// ---------------- plain m97-style bf16 GEMM (for ixfx) ----------------
__global__ __launch_bounds__(256) void gemm_bt_plain(
    const ushort* __restrict__ A, const ushort* __restrict__ B,
    float* __restrict__ C, int N, int K, int NTN)
{
  __shared__ ushort lA[128*32];
  __shared__ ushort lB[128*32];
  int tid = threadIdx.x;
  int lane = tid & 63, wid = tid >> 6;
  int tm = blockIdx.x / NTN, tn = blockIdx.x % NTN;
  int row0 = tm << 7, col0 = tn << 7;

  f32x4 acc[4][4] = {};

  auto stage = [&](const ushort* __restrict__ g, ushort* l, int r0, int k0){
    int c = wid << 1;
    const ushort* s0 = g + (size_t)(r0 + (c<<4) + (lane>>2))*K + k0 + ((lane&3)<<3);
    async_copy16(l + (c<<9), s0);
    async_copy16(l + ((c+1)<<9), s0 + (size_t)16*K);
  };

  int nk = K >> 5;
  stage(A, lA, row0, 0);
  stage(B, lB, col0, 0);
  int wm = (wid >> 1) << 6, wn = (wid & 1) << 6;
  int kg = (lane >> 4) << 3;
  int ar = lane & 15;

  for (int kt = 0; kt < nk; ++kt){
    __syncthreads();
    bf16x8 af[4], bfr[4];
    #pragma unroll
    for (int mi = 0; mi < 4; ++mi) af[mi]  = *(const bf16x8*)&lA[(wm + mi*16 + ar)*32 + kg];
    #pragma unroll
    for (int ni = 0; ni < 4; ++ni) bfr[ni] = *(const bf16x8*)&lB[(wn + ni*16 + ar)*32 + kg];
    #pragma unroll
    for (int mi = 0; mi < 4; ++mi)
      #pragma unroll
      for (int ni = 0; ni < 4; ++ni)
        acc[mi][ni] = __builtin_amdgcn_mfma_f32_16x16x32_bf16(af[mi], bfr[ni], acc[mi][ni], 0, 0, 0);
    if (kt + 1 < nk){
      __syncthreads();
      stage(A, lA, row0, (kt+1) << 5);
      stage(B, lB, col0, (kt+1) << 5);
    }
  }

  int rr = (lane >> 4) << 2;
  #pragma unroll
  for (int mi = 0; mi < 4; ++mi)
    #pragma unroll
    for (int ni = 0; ni < 4; ++ni){
      int r  = row0 + wm + mi*16 + rr;
      int cc = col0 + wn + ni*16 + ar;
      #pragma unroll
      for (int q = 0; q < 4; ++q)
        C[(size_t)(r + q) * N + cc] = acc[mi][ni][q];
    }
}

// ---------------- Vproj: 256x256-tile, BK=32, depth-3 counted-vmcnt pipeline ----------------
// C[4096][32000] = A(cstate chunked)[4096][1024] * B[32000][1024]^T + bias, fused LSE partials.
// A chunked: row r -> t=r>>5, m=r&31; elem addr = t*32768 + (k>>4)*512 + m*16 + (k&15).
// 32 K-tiles in 4 LDS slots; per tile: vmcnt(8) gate -> barrier -> STAGE(t+3) -> reads -> MFMA.
// Stage AFTER barrier makes slot (t+3)&3 (= tile t-1's slot) WAR-safe at depth 3.
// Granule swizzle phys = conc ^ ((row>>1)&3).
__global__ __launch_bounds__(512) void gemm256(
    const ushort* __restrict__ A, const ushort* __restrict__ B,
    float* __restrict__ C, const float* __restrict__ bias,
    float* __restrict__ pmax, float* __restrict__ psum)
{
  __shared__ ushort lA[4][256*GBK];
  __shared__ ushort lB[4][256*GBK];
  __shared__ float redm[2][4][128], reds[2][4][128];

  const int K = 1024, N = V_DIM, NTN = 125, NT = 32;
  int tid = threadIdx.x, lane = tid & 63, wid = tid >> 6;
  int wm = wid >> 2, wn = wid & 3;
  int bid = blockIdx.x;
  int xcd = bid & 7, id = bid >> 3;       // 2000 blocks: 250 per XCD
  int tm = (xcd << 1) | (id & 1);         // 2 M-bands per XCD (A band L2-resident)
  int tn = id >> 1;                       // 125 N-tiles
  int row0 = tm << 8, col0 = tn << 8;
  int ar = lane & 15, kg = (lane >> 4) << 3;

  auto STAGE = [&](int slot, int kt){
    int k0 = kt << 5;
    #pragma unroll
    for (int j = 0; j < 2; ++j){
      int u = j*512 + tid;                 // A 16B unit: 1024 units
      int r = u >> 2, p = u & 3;           // row, physical granule
      int g = p ^ ((r >> 1) & 3);          // conceptual granule
      int rA = row0 + r, k = k0 + (g << 3);
      const ushort* sA = A + ((size_t)(rA>>5)<<15) + ((size_t)(k>>4)<<9) + ((rA&31)<<4) + (k&15);
      async_copy16(&lA[slot][u<<3], sA);
    }
    #pragma unroll
    for (int j = 0; j < 2; ++j){
      int u = j*512 + tid;
      int r = u >> 2, p = u & 3;
      int g = p ^ ((r >> 1) & 3);
      const ushort* sB = B + (size_t)(col0 + r)*K + k0 + (g << 3);
      async_copy16(&lB[slot][u<<3], sB);
    }
  };

  f32x4 acc[8][4] = {};

  STAGE(0, 0);
  STAGE(1, 1);
  STAGE(2, 2);
  int gk = kg >> 3;                        // conceptual granule of this lane group
  for (int t = 0; t < NT; ++t){
    if (t + 2 < NT)      asm volatile("s_waitcnt vmcnt(8)" ::: "memory");
    else if (t + 1 < NT) asm volatile("s_waitcnt vmcnt(4)" ::: "memory");
    else                 asm volatile("s_waitcnt vmcnt(0)" ::: "memory");
    __builtin_amdgcn_s_barrier();
    __builtin_amdgcn_sched_barrier(0);
    if (t + 3 < NT) STAGE((t+3) & 3, t+3);   // after barrier: WAR-safe vs tile t-1 reads
    const ushort* bufA = lA[t & 3];
    const ushort* bufB = lB[t & 3];
    bf16x8 a[8], b[4];
    #pragma unroll
    for (int fr = 0; fr < 8; ++fr){
      int row = wm*128 + fr*16 + ar;
      int phys = gk ^ ((row >> 1) & 3);
      a[fr] = *(const bf16x8*)&bufA[row*GBK + (phys << 3)];
    }
    #pragma unroll
    for (int fc = 0; fc < 4; ++fc){
      int row = wn*64 + fc*16 + ar;
      int phys = gk ^ ((row >> 1) & 3);
      b[fc] = *(const bf16x8*)&bufB[row*GBK + (phys << 3)];
    }
    __builtin_amdgcn_s_setprio(1);
    #pragma unroll
    for (int fr = 0; fr < 8; ++fr)
      #pragma unroll
      for (int fc = 0; fc < 4; ++fc)
        acc[fr][fc] = __builtin_amdgcn_mfma_f32_16x16x32_bf16(a[fr], b[fc], acc[fr][fc], 0, 0, 0);
    __builtin_amdgcn_s_setprio(0);
    __builtin_amdgcn_sched_barrier(0);
  }

  // epilogue: bias + C-write + per-(row, tile) LSE partials
  float bb4[4];
  #pragma unroll
  for (int fc = 0; fc < 4; ++fc) bb4[fc] = bias[col0 + wn*64 + fc*16 + ar];
  #pragma unroll
  for (int fr = 0; fr < 8; ++fr){
    #pragma unroll
    for (int q = 0; q < 4; ++q){
      int rl = fr*16 + (lane>>4)*4 + q;
      int r = row0 + wm*128 + rl;
      float vals[4];
      #pragma unroll
      for (int fc = 0; fc < 4; ++fc){
        vals[fc] = acc[fr][fc][q] + bb4[fc];
        C[(size_t)r * N + col0 + wn*64 + fc*16 + ar] = vals[fc];
      }
      float m = fmaxf(fmaxf(vals[0], vals[1]), fmaxf(vals[2], vals[3]));
      #pragma unroll
      for (int o = 1; o < 16; o <<= 1) m = fmaxf(m, __shfl_xor(m, o));
      float s = expf(vals[0]-m) + expf(vals[1]-m) + expf(vals[2]-m) + expf(vals[3]-m);
      #pragma unroll
      for (int o = 1; o < 16; o <<= 1) s += __shfl_xor(s, o);
      if (ar == 0){ redm[wm][wn][rl] = m; reds[wm][wn][rl] = s; }
    }
  }
  __syncthreads();
  if (tid < 256){
    int wm2 = tid >> 7, rl = tid & 127;
    float m0 = redm[wm2][0][rl], m1 = redm[wm2][1][rl];
    float m2 = redm[wm2][2][rl], m3 = redm[wm2][3][rl];
    float M = fmaxf(fmaxf(m0, m1), fmaxf(m2, m3));
    float S = reds[wm2][0][rl]*expf(m0-M) + reds[wm2][1][rl]*expf(m1-M)
            + reds[wm2][2][rl]*expf(m2-M) + reds[wm2][3][rl]*expf(m3-M);
    int r = row0 + wm2*128 + rl;
    pmax[(size_t)r*NTN + tn] = M;
    psum[(size_t)r*NTN + tn] = S;
  }
}

// ---------------- persistent recurrence: tagged dataflow + untagged dual-store ----------------
__global__ __launch_bounds__(512) void ran_all(
    unsigned* __restrict__ pub, ushort* __restrict__ cst,
    const float* __restrict__ hiddenf,
    const ushort* __restrict__ wh, const ushort* __restrict__ wl,
    const float* __restrict__ b_i, const float* __restrict__ b_f,
    const float* __restrict__ ixfx, const float* __restrict__ x_all,
    float* __restrict__ hid_final)
{
  __shared__ ushort lWh[32*WSTRIDE];
  __shared__ ushort lWl[32*WSTRIDE];
  __shared__ f32x4 part[4][2][2][64];   // [kq][mh][gate][lane]
  __shared__ float gsm[2*32*17];
  __shared__ float cfl[32][17];

  int tid = threadIdx.x, lane = tid & 63, wid = tid >> 6;
  int kq = wid & 3, mh = wid >> 2;           // MFMA roles
  int rgate = wid & 1, rmh = (wid >> 1) & 1; // reduce roles (wid<4)
  int bid = blockIdx.x;
  int nb = bid << 4;
  int ar = lane & 15, kg = (lane >> 4) << 3;
  int um = tid >> 4, uk = tid & 15;

  #pragma unroll
  for (int u = 0; u < 8; ++u){
    int unit = u*512 + tid;
    int r = unit >> 7, off = (unit & 127) << 3;
    int g = r >> 4, c = r & 15;
    size_t gsrc = (size_t)((g<<10) + nb + c) * H_DIM + off;
    *(bf16x8*)&lWh[r*WSTRIDE + off] = *(const bf16x8*)&wh[gsrc];
    *(bf16x8*)&lWl[r*WSTRIDE + off] = *(const bf16x8*)&wl[gsrc];
  }
  cfl[um][uk] = hiddenf[(um<<10) + nb + uk];
  float bb = (rgate ? b_f : b_i)[nb + ar];
  const ushort* b0h = &lWh[(     ar)*WSTRIDE + (kq<<8) + kg];
  const ushort* b0l = &lWl[(     ar)*WSTRIDE + (kq<<8) + kg];
  const ushort* b1h = &lWh[(16 + ar)*WSTRIDE + (kq<<8) + kg];
  const ushort* b1l = &lWl[(16 + ar)*WSTRIDE + (kq<<8) + kg];
  int abase = (kq<<13) + ((kg>>4)<<9) + (((mh<<4) + ar)<<4) + (kg & 8);
  __syncthreads();

  for (int t = 0; t < T_DIM; ++t){
    float xq1 = x_all[((size_t)t<<15) + (um<<10) + nb + uk];
    float pix[4];
    if (wid < 4){
      const float* ix_t = ixfx + ((size_t)t<<16);
      #pragma unroll
      for (int q = 0; q < 4; ++q){
        int m = (rmh<<4) + ((lane>>4)<<2) + q;
        pix[q] = ix_t[m*2048 + (rgate<<10) + nb + ar];
      }
    }

    const unsigned* ps = pub + ((size_t)t << 15) + abase;
    unsigned expt = (unsigned)(t + 1) << 16;
    u32x4 w0[8], w1[8];
    int tries = 0;
    while (1){
      #pragma unroll
      for (int f = 0; f < 8; ++f){
        const unsigned* p = ps + (f << 10);
        asm volatile("global_load_dwordx4 %0, %2, off sc0 sc1\n\t"
                     "global_load_dwordx4 %1, %2, off offset:16 sc0 sc1"
                     : "=&v"(w0[f]), "=&v"(w1[f]) : "v"(p));
      }
      asm volatile("s_waitcnt vmcnt(0)" ::: "memory");
      __builtin_amdgcn_sched_barrier(0);
      unsigned bad = 0;
      #pragma unroll
      for (int f = 0; f < 8; ++f){
        bad |= (w0[f][0]^expt)|(w0[f][1]^expt)|(w0[f][2]^expt)|(w0[f][3]^expt)
             | (w1[f][0]^expt)|(w1[f][1]^expt)|(w1[f][2]^expt)|(w1[f][3]^expt);
      }
      if (__ballot((bad & 0xFFFF0000u) != 0) == 0ull) break;
      if (++tries > (1<<15)) break;   // bounded: fail fast, not hang
    }

    f32x4 g0h = {}, g0l = {}, g1h = {}, g1l = {};
    #pragma unroll
    for (int f = 0; f < 8; ++f){
      union { unsigned u[4]; bf16x8 v; } cv;
      cv.u[0] = (w0[f][0] & 0xFFFFu) | (w0[f][1] << 16);
      cv.u[1] = (w0[f][2] & 0xFFFFu) | (w0[f][3] << 16);
      cv.u[2] = (w1[f][0] & 0xFFFFu) | (w1[f][1] << 16);
      cv.u[3] = (w1[f][2] & 0xFFFFu) | (w1[f][3] << 16);
      int ob = f << 5;
      bf16x8 v0h = *(const bf16x8*)&b0h[ob];
      bf16x8 v0l = *(const bf16x8*)&b0l[ob];
      bf16x8 v1h = *(const bf16x8*)&b1h[ob];
      bf16x8 v1l = *(const bf16x8*)&b1l[ob];
      g0h = __builtin_amdgcn_mfma_f32_16x16x32_bf16(cv.v, v0h, g0h, 0, 0, 0);
      g0l = __builtin_amdgcn_mfma_f32_16x16x32_bf16(cv.v, v0l, g0l, 0, 0, 0);
      g1h = __builtin_amdgcn_mfma_f32_16x16x32_bf16(cv.v, v1h, g1h, 0, 0, 0);
      g1l = __builtin_amdgcn_mfma_f32_16x16x32_bf16(cv.v, v1l, g1l, 0, 0, 0);
    }
    part[kq][mh][0][lane] = g0h + g0l;
    part[kq][mh][1][lane] = g1h + g1l;
    __syncthreads();

    if (wid < 4){
      f32x4 sum = part[0][rmh][rgate][lane] + part[1][rmh][rgate][lane]
                + part[2][rmh][rgate][lane] + part[3][rmh][rgate][lane];
      #pragma unroll
      for (int q = 0; q < 4; ++q){
        int m = (rmh<<4) + ((lane>>4)<<2) + q;
        float pre = sum[q] + bb + pix[q];
        gsm[((rgate<<5) + m)*17 + ar] = 1.f / (1.f + expf(-pre));
      }
    }
    __syncthreads();

    {
      float iv = gsm[um*17 + uk];
      float fv = gsm[(32+um)*17 + uk];
      float cv2 = cfl[um][uk];
      float cn = iv * xq1 + fv * cv2;
      cfl[um][uk] = cn;
      ushort hb = f2bf(cn);
      unsigned word = ((unsigned)(t + 2) << 16) | (unsigned)hb;
      __hip_atomic_store(&pub[((size_t)(t+1) << 15) + (bid << 9) + tid], word,
                         __ATOMIC_RELAXED, __HIP_MEMORY_SCOPE_AGENT);
      cst[((size_t)t << 15) + (bid << 9) + tid] = hb;  // untagged copy for gemm256
      if (t == T_DIM-1) hid_final[(um<<10) + nb + uk] = cn;
    }
    __syncthreads();
  }
}

// init: write tagged c_init into pub slot 0 (tag = 1)
__global__ void init_c_kernel(const float* __restrict__ hidden, unsigned* __restrict__ pub){
  int i = blockIdx.x * blockDim.x + threadIdx.x;   // 0..32767
  float v = hidden[i];
  int m = i >> 10, col = i & 1023;
  pub[((col>>4)<<9) + (m<<4) + (col&15)] = (1u << 16) | (unsigned)f2bf(v);
}

// ---------------- fused lse + subtract: one block per row ----------------
__global__ __launch_bounds__(256) void subf_kernel(float* __restrict__ logits,
                                                   const float* __restrict__ pmax,
                                                   const float* __restrict__ psum){
  __shared__ float sl;
  size_t row = blockIdx.x;
  int tid = threadIdx.x;
  if (tid < 64){
    float m = -1e30f, s = 0.f;
    for (int i = tid; i < 125; i += 64){
      float mi = pmax[row*125 + i], si = psum[row*125 + i];
      float M = fmaxf(m, mi);
      s = s*expf(m - M) + si*expf(mi - M);
      m = M;
    }
    #pragma unroll
    for (int o = 32; o; o >>= 1){
      float m2 = __shfl_xor(m, o), s2 = __shfl_xor(s, o);
      float M = fmaxf(m, m2);
      s = s*expf(m - M) + s2*expf(m2 - M);
      m = M;
    }
    if (tid == 0) sl = m + logf(s);
  }
  __syncthreads();
  float l = sl;
  float4* p4 = (float4*)(logits + row * (size_t)V_DIM);
  for (int i = tid; i < V_DIM/4; i += 256){
    float4 v = p4[i];
    v.x -= l; v.y -= l; v.z -= l; v.w -= l;
    p4[i] = v;
  }
}

// ---------------- launch ----------------
extern "C" void kernel_launch(void* const* d_in, const int* in_sizes, int n_in,
                              void* d_out, int out_size, void* d_ws, size_t ws_size,
                              hipStream_t stream)
{
  const float* input  = (const float*)d_in[0];
  const float* hidden = (const float*)d_in[1];
  const float* w_ic   = (const float*)d_in[2];
  const float* w_ix   = (const float*)d_in[3];
  const float* w_fc   = (const float*)d_in[4];
  const float* w_fx   = (const float*)d_in[5];
  const float* b_i    = (const float*)d_in[6];
  const float* b_f    = (const float*)d_in[7];
  const float* W_out  = (const float*)d_in[8];
  const float* b_out  = (const float*)d_in[9];
  float* out = (float*)d_out;

  char* ws = (char*)d_ws;
  ushort* wout_bf = (ushort*)(ws + 0);          // 0 .. 65,536,000
  ushort* in_hi   = (ushort*)(ws + 65536000);   // 8,388,608 (dead after ixfx gemm)
  ushort* wx      = (ushort*)(ws + 73924608);   // [w_ix; w_fx] plain bf16, 4,194,304
  ushort* wc_hi   = (ushort*)(ws + 90701824);   // split W for recurrence
  ushort* wc_lo   = (ushort*)(ws + 94896128);
  // overlays (regions dead at time of use):
  unsigned* pub   = (unsigned*)(ws + 65536000); // [129][32768] tagged c, 16,908,288 B
  ushort* cstate  = (ushort*)(ws + 82444288);   // [128][32768] bf16; tail 131KB overlaps wc_hi
                                                //   but only written at t>=126 (W-LDS copies done)
  float*  pmax    = (float*)(ws + 94896128);    // [4096][125] over wc_lo (dead post-ran_all)
  float*  psum    = (float*)(ws + 99090432);
  float*  ixfx    = out;                        // [4096][2048] scratch in logits region

  cast_bf16_kernel<<<2048,256,0,stream>>>(W_out, wout_bf, V_DIM*H_DIM/4);
  cast_bf16_kernel<<<1024,256,0,stream>>>(input, in_hi, MROWS*H_DIM/4);
  cast_bf16_kernel<<<256,256,0,stream>>>(w_ix, wx,             H_DIM*H_DIM/4);
  cast_bf16_kernel<<<256,256,0,stream>>>(w_fx, wx+H_DIM*H_DIM, H_DIM*H_DIM/4);
  cast_split_kernel<<<256,256,0,stream>>>(w_ic, wc_hi,             wc_lo,             H_DIM*H_DIM/4);
  cast_split_kernel<<<256,256,0,stream>>>(w_fc, wc_hi+H_DIM*H_DIM, wc_lo+H_DIM*H_DIM, H_DIM*H_DIM/4);

  // ixfx = input @ [w_ix; w_fx]^T (plain bf16) — before pub overlays in_hi/wx
  gemm_bt_plain<<<32*16,256,0,stream>>>(in_hi, wx, ixfx, 2048, H_DIM, 16);

  // clear tags (graph-replay safety), seed slot 0
  hipMemsetAsync(pub, 0, (size_t)129 * PUBSTEP * 4, stream);
  init_c_kernel<<<128,256,0,stream>>>(hidden, pub);

  ran_all<<<NBLK,512,0,stream>>>(pub, cstate, hidden, wc_hi, wc_lo, b_i, b_f,
                                 ixfx, input, out + (size_t)MROWS*V_DIM);

  // depth-3 pipelined 256^2 logits GEMM + fused LSE partials (reads cstate directly)
  gemm256<<<2000,512,0,stream>>>(cstate, wout_bf, out, b_out, pmax, psum);
  subf_kernel<<<MROWS,256,0,stream>>>(out, pmax, psum);
}

// Round 15
// 1867.469 us; speedup vs baseline: 1.0581x; 1.0409x over previous
//
#include <hip/hip_runtime.h>

typedef __attribute__((ext_vector_type(4))) float f32x4;
typedef __attribute__((ext_vector_type(8))) short bf16x8;
typedef __attribute__((ext_vector_type(4))) unsigned u32x4;

#define T_DIM 128
#define B_DIM 32
#define H_DIM 1024
#define V_DIM 32000
#define MROWS 4096    // T*B
#define NBLK 64       // persistent recurrence blocks
#define PUBSTEP 32768 // dwords per slot in tagged pub buffer
#define WSTRIDE 1028  // LDS W row stride (ushorts): bank step 2 -> conflict-free
#define GBK 32        // gemm256 K-tile

__device__ __forceinline__ ushort f2bf(float f){
  union { float f; unsigned u; } x; x.f = f;
  unsigned u = x.u;
  unsigned r = (u + 0x7fffu + ((u >> 16) & 1u)) >> 16;
  return (ushort)r;
}
__device__ __forceinline__ float bf2f(ushort h){
  union { unsigned u; float f; } x; x.u = ((unsigned)h) << 16;
  return x.f;
}

__device__ __forceinline__ void async_copy16(void* lds, const void* g){
  __builtin_amdgcn_global_load_lds((const __attribute__((address_space(1))) void*)g,
                                   (__attribute__((address_space(3))) void*)lds, 16, 0, 0);
}

// ---------------- casts ----------------
__global__ void cast_bf16_kernel(const float* __restrict__ s, ushort* __restrict__ d, int n4){
  int stride = gridDim.x * blockDim.x;
  for (int i = blockIdx.x*blockDim.x + threadIdx.x; i < n4; i += stride){
    float4 v = ((const float4*)s)[i];
    ushort4 o = make_ushort4(f2bf(v.x), f2bf(v.y), f2bf(v.z), f2bf(v.w));
    ((ushort4*)d)[i] = o;
  }
}

__global__ void cast_split_kernel(const float* __restrict__ s, ushort* __restrict__ dh,
                                  ushort* __restrict__ dl, int n4){
  int stride = gridDim.x * blockDim.x;
  for (int i = blockIdx.x*blockDim.x + threadIdx.x; i < n4; i += stride){
    float4 v = ((const float4*)s)[i];
    ushort4 h = make_ushort4(f2bf(v.x), f2bf(v.y), f2bf(v.z), f2bf(v.w));
    ushort4 l = make_ushort4(f2bf(v.x - bf2f(h.x)), f2bf(v.y - bf2f(h.y)),
                             f2bf(v.z - bf2f(h.z)), f2bf(v.w - bf2f(h.w)));
    ((ushort4*)dh)[i] = h;
    ((ushort4*)dl)[i] = l;
  }
}

// ---------------- plain m97-style bf16 GEMM (for ixfx) ----------------
__global__ __launch_bounds__(256) void gemm_bt_plain(
    const ushort* __restrict__ A, const ushort* __restrict__ B,
    float* __restrict__ C, int N, int K, int NTN)
{
  __shared__ ushort lA[128*32];
  __shared__ ushort lB[128*32];
  int tid = threadIdx.x;
  int lane = tid & 63, wid = tid >> 6;
  int tm = blockIdx.x / NTN, tn = blockIdx.x % NTN;
  int row0 = tm << 7, col0 = tn << 7;

  f32x4 acc[4][4] = {};

  auto stage = [&](const ushort* __restrict__ g, ushort* l, int r0, int k0){
    int c = wid << 1;
    const ushort* s0 = g + (size_t)(r0 + (c<<4) + (lane>>2))*K + k0 + ((lane&3)<<3);
    async_copy16(l + (c<<9), s0);
    async_copy16(l + ((c+1)<<9), s0 + (size_t)16*K);
  };

  int nk = K >> 5;
  stage(A, lA, row0, 0);
  stage(B, lB, col0, 0);
  int wm = (wid >> 1) << 6, wn = (wid & 1) << 6;
  int kg = (lane >> 4) << 3;
  int ar = lane & 15;

  for (int kt = 0; kt < nk; ++kt){
    __syncthreads();
    bf16x8 af[4], bfr[4];
    #pragma unroll
    for (int mi = 0; mi < 4; ++mi) af[mi]  = *(const bf16x8*)&lA[(wm + mi*16 + ar)*32 + kg];
    #pragma unroll
    for (int ni = 0; ni < 4; ++ni) bfr[ni] = *(const bf16x8*)&lB[(wn + ni*16 + ar)*32 + kg];
    #pragma unroll
    for (int mi = 0; mi < 4; ++mi)
      #pragma unroll
      for (int ni = 0; ni < 4; ++ni)
        acc[mi][ni] = __builtin_amdgcn_mfma_f32_16x16x32_bf16(af[mi], bfr[ni], acc[mi][ni], 0, 0, 0);
    if (kt + 1 < nk){
      __syncthreads();
      stage(A, lA, row0, (kt+1) << 5);
      stage(B, lB, col0, (kt+1) << 5);
    }
  }

  int rr = (lane >> 4) << 2;
  #pragma unroll
  for (int mi = 0; mi < 4; ++mi)
    #pragma unroll
    for (int ni = 0; ni < 4; ++ni){
      int r  = row0 + wm + mi*16 + rr;
      int cc = col0 + wn + ni*16 + ar;
      #pragma unroll
      for (int q = 0; q < 4; ++q)
        C[(size_t)(r + q) * N + cc] = acc[mi][ni][q];
    }
}

// ---------------- Vproj: 256x256-tile, BK=32, depth-2 counted-vmcnt (r12-exact) ----------------
// C[4096][32000] = A(cstate chunked)[4096][1024] * B[32000][1024]^T + bias, fused LSE partials.
// A chunked: row r -> t=r>>5, m=r&31; elem addr = t*32768 + (k>>4)*512 + m*16 + (k&15).
// 32 K-tiles in 4 LDS slots; STAGE(t+2) issued BEFORE the vmcnt gate (addr calc + issue
// overlap the stall — depth-3 stage-after-barrier measured -88us, r14). vmcnt(8) drains
// tile t's 4 oldest loads. Granule swizzle phys = conc ^ ((row>>1)&3).
__global__ __launch_bounds__(512) void gemm256(
    const ushort* __restrict__ A, const ushort* __restrict__ B,
    float* __restrict__ C, const float* __restrict__ bias,
    float* __restrict__ pmax, float* __restrict__ psum)
{
  __shared__ ushort lA[4][256*GBK];
  __shared__ ushort lB[4][256*GBK];
  __shared__ float redm[2][4][128], reds[2][4][128];

  const int K = 1024, N = V_DIM, NTN = 125, NT = 32;
  int tid = threadIdx.x, lane = tid & 63, wid = tid >> 6;
  int wm = wid >> 2, wn = wid & 3;
  int bid = blockIdx.x;
  int xcd = bid & 7, id = bid >> 3;       // 2000 blocks: 250 per XCD
  int tm = (xcd << 1) | (id & 1);         // 2 M-bands per XCD (A band L2-resident)
  int tn = id >> 1;                       // 125 N-tiles
  int row0 = tm << 8, col0 = tn << 8;
  int ar = lane & 15, kg = (lane >> 4) << 3;

  auto STAGE = [&](int slot, int kt){
    int k0 = kt << 5;
    #pragma unroll
    for (int j = 0; j < 2; ++j){
      int u = j*512 + tid;                 // A 16B unit: 1024 units
      int r = u >> 2, p = u & 3;           // row, physical granule
      int g = p ^ ((r >> 1) & 3);          // conceptual granule
      int rA = row0 + r, k = k0 + (g << 3);
      const ushort* sA = A + ((size_t)(rA>>5)<<15) + ((size_t)(k>>4)<<9) + ((rA&31)<<4) + (k&15);
      async_copy16(&lA[slot][u<<3], sA);
    }
    #pragma unroll
    for (int j = 0; j < 2; ++j){
      int u = j*512 + tid;
      int r = u >> 2, p = u & 3;
      int g = p ^ ((r >> 1) & 3);
      const ushort* sB = B + (size_t)(col0 + r)*K + k0 + (g << 3);
      async_copy16(&lB[slot][u<<3], sB);
    }
  };

  f32x4 acc[8][4] = {};

  STAGE(0, 0);
  STAGE(1, 1);
  int gk = kg >> 3;                        // conceptual granule of this lane group
  for (int t = 0; t < NT; ++t){
    if (t + 2 < NT) STAGE((t+2) & 3, t+2);
    if (t + 2 < NT)      asm volatile("s_waitcnt vmcnt(8)" ::: "memory");
    else if (t + 1 < NT) asm volatile("s_waitcnt vmcnt(4)" ::: "memory");
    else                 asm volatile("s_waitcnt vmcnt(0)" ::: "memory");
    __builtin_amdgcn_s_barrier();
    __builtin_amdgcn_sched_barrier(0);
    const ushort* bufA = lA[t & 3];
    const ushort* bufB = lB[t & 3];
    bf16x8 a[8], b[4];
    #pragma unroll
    for (int fr = 0; fr < 8; ++fr){
      int row = wm*128 + fr*16 + ar;
      int phys = gk ^ ((row >> 1) & 3);
      a[fr] = *(const bf16x8*)&bufA[row*GBK + (phys << 3)];
    }
    #pragma unroll
    for (int fc = 0; fc < 4; ++fc){
      int row = wn*64 + fc*16 + ar;
      int phys = gk ^ ((row >> 1) & 3);
      b[fc] = *(const bf16x8*)&bufB[row*GBK + (phys << 3)];
    }
    __builtin_amdgcn_s_setprio(1);
    #pragma unroll
    for (int fr = 0; fr < 8; ++fr)
      #pragma unroll
      for (int fc = 0; fc < 4; ++fc)
        acc[fr][fc] = __builtin_amdgcn_mfma_f32_16x16x32_bf16(a[fr], b[fc], acc[fr][fc], 0, 0, 0);
    __builtin_amdgcn_s_setprio(0);
    __builtin_amdgcn_sched_barrier(0);
  }

  // epilogue: bias + C-write + per-(row, tile) LSE partials
  float bb4[4];
  #pragma unroll
  for (int fc = 0; fc < 4; ++fc) bb4[fc] = bias[col0 + wn*64 + fc*16 + ar];
  #pragma unroll
  for (int fr = 0; fr < 8; ++fr){
    #pragma unroll
    for (int q = 0; q < 4; ++q){
      int rl = fr*16 + (lane>>4)*4 + q;
      int r = row0 + wm*128 + rl;
      float vals[4];
      #pragma unroll
      for (int fc = 0; fc < 4; ++fc){
        vals[fc] = acc[fr][fc][q] + bb4[fc];
        C[(size_t)r * N + col0 + wn*64 + fc*16 + ar] = vals[fc];
      }
      float m = fmaxf(fmaxf(vals[0], vals[1]), fmaxf(vals[2], vals[3]));
      #pragma unroll
      for (int o = 1; o < 16; o <<= 1) m = fmaxf(m, __shfl_xor(m, o));
      float s = expf(vals[0]-m) + expf(vals[1]-m) + expf(vals[2]-m) + expf(vals[3]-m);
      #pragma unroll
      for (int o = 1; o < 16; o <<= 1) s += __shfl_xor(s, o);
      if (ar == 0){ redm[wm][wn][rl] = m; reds[wm][wn][rl] = s; }
    }
  }
  __syncthreads();
  if (tid < 256){
    int wm2 = tid >> 7, rl = tid & 127;
    float m0 = redm[wm2][0][rl], m1 = redm[wm2][1][rl];
    float m2 = redm[wm2][2][rl], m3 = redm[wm2][3][rl];
    float M = fmaxf(fmaxf(m0, m1), fmaxf(m2, m3));
    float S = reds[wm2][0][rl]*expf(m0-M) + reds[wm2][1][rl]*expf(m1-M)
            + reds[wm2][2][rl]*expf(m2-M) + reds[wm2][3][rl]*expf(m3-M);
    int r = row0 + wm2*128 + rl;
    pmax[(size_t)r*NTN + tn] = M;
    psum[(size_t)r*NTN + tn] = S;
  }
}

// ---------------- persistent recurrence: tagged dataflow + untagged dual-store ----------------
__global__ __launch_bounds__(512) void ran_all(
    unsigned* __restrict__ pub, ushort* __restrict__ cst,
    const float* __restrict__ hiddenf,
    const ushort* __restrict__ wh, const ushort* __restrict__ wl,
    const float* __restrict__ b_i, const float* __restrict__ b_f,
    const float* __restrict__ ixfx, const float* __restrict__ x_all,
    float* __restrict__ hid_final)
{
  __shared__ ushort lWh[32*WSTRIDE];
  __shared__ ushort lWl[32*WSTRIDE];
  __shared__ f32x4 part[4][2][2][64];   // [kq][mh][gate][lane]
  __shared__ float gsm[2*32*17];
  __shared__ float cfl[32][17];

  int tid = threadIdx.x, lane = tid & 63, wid = tid >> 6;
  int kq = wid & 3, mh = wid >> 2;           // MFMA roles
  int rgate = wid & 1, rmh = (wid >> 1) & 1; // reduce roles (wid<4)
  int bid = blockIdx.x;
  int nb = bid << 4;
  int ar = lane & 15, kg = (lane >> 4) << 3;
  int um = tid >> 4, uk = tid & 15;

  #pragma unroll
  for (int u = 0; u < 8; ++u){
    int unit = u*512 + tid;
    int r = unit >> 7, off = (unit & 127) << 3;
    int g = r >> 4, c = r & 15;
    size_t gsrc = (size_t)((g<<10) + nb + c) * H_DIM + off;
    *(bf16x8*)&lWh[r*WSTRIDE + off] = *(const bf16x8*)&wh[gsrc];
    *(bf16x8*)&lWl[r*WSTRIDE + off] = *(const bf16x8*)&wl[gsrc];
  }
  cfl[um][uk] = hiddenf[(um<<10) + nb + uk];
  float bb = (rgate ? b_f : b_i)[nb + ar];
  const ushort* b0h = &lWh[(     ar)*WSTRIDE + (kq<<8) + kg];
  const ushort* b0l = &lWl[(     ar)*WSTRIDE + (kq<<8) + kg];
  const ushort* b1h = &lWh[(16 + ar)*WSTRIDE + (kq<<8) + kg];
  const ushort* b1l = &lWl[(16 + ar)*WSTRIDE + (kq<<8) + kg];
  int abase = (kq<<13) + ((kg>>4)<<9) + (((mh<<4) + ar)<<4) + (kg & 8);
  __syncthreads();

  for (int t = 0; t < T_DIM; ++t){
    float xq1 = x_all[((size_t)t<<15) + (um<<10) + nb + uk];
    float pix[4];
    if (wid < 4){
      const float* ix_t = ixfx + ((size_t)t<<16);
      #pragma unroll
      for (int q = 0; q < 4; ++q){
        int m = (rmh<<4) + ((lane>>4)<<2) + q;
        pix[q] = ix_t[m*2048 + (rgate<<10) + nb + ar];
      }
    }

    const unsigned* ps = pub + ((size_t)t << 15) + abase;
    unsigned expt = (unsigned)(t + 1) << 16;
    u32x4 w0[8], w1[8];
    int tries = 0;
    while (1){
      #pragma unroll
      for (int f = 0; f < 8; ++f){
        const unsigned* p = ps + (f << 10);
        asm volatile("global_load_dwordx4 %0, %2, off sc0 sc1\n\t"
                     "global_load_dwordx4 %1, %2, off offset:16 sc0 sc1"
                     : "=&v"(w0[f]), "=&v"(w1[f]) : "v"(p));
      }
      asm volatile("s_waitcnt vmcnt(0)" ::: "memory");
      __builtin_amdgcn_sched_barrier(0);
      unsigned bad = 0;
      #pragma unroll
      for (int f = 0; f < 8; ++f){
        bad |= (w0[f][0]^expt)|(w0[f][1]^expt)|(w0[f][2]^expt)|(w0[f][3]^expt)
             | (w1[f][0]^expt)|(w1[f][1]^expt)|(w1[f][2]^expt)|(w1[f][3]^expt);
      }
      if (__ballot((bad & 0xFFFF0000u) != 0) == 0ull) break;
      if (++tries > (1<<15)) break;   // bounded: fail fast, not hang
    }

    f32x4 g0h = {}, g0l = {}, g1h = {}, g1l = {};
    #pragma unroll
    for (int f = 0; f < 8; ++f){
      union { unsigned u[4]; bf16x8 v; } cv;
      cv.u[0] = (w0[f][0] & 0xFFFFu) | (w0[f][1] << 16);
      cv.u[1] = (w0[f][2] & 0xFFFFu) | (w0[f][3] << 16);
      cv.u[2] = (w1[f][0] & 0xFFFFu) | (w1[f][1] << 16);
      cv.u[3] = (w1[f][2] & 0xFFFFu) | (w1[f][3] << 16);
      int ob = f << 5;
      bf16x8 v0h = *(const bf16x8*)&b0h[ob];
      bf16x8 v0l = *(const bf16x8*)&b0l[ob];
      bf16x8 v1h = *(const bf16x8*)&b1h[ob];
      bf16x8 v1l = *(const bf16x8*)&b1l[ob];
      g0h = __builtin_amdgcn_mfma_f32_16x16x32_bf16(cv.v, v0h, g0h, 0, 0, 0);
      g0l = __builtin_amdgcn_mfma_f32_16x16x32_bf16(cv.v, v0l, g0l, 0, 0, 0);
      g1h = __builtin_amdgcn_mfma_f32_16x16x32_bf16(cv.v, v1h, g1h, 0, 0, 0);
      g1l = __builtin_amdgcn_mfma_f32_16x16x32_bf16(cv.v, v1l, g1l, 0, 0, 0);
    }
    part[kq][mh][0][lane] = g0h + g0l;
    part[kq][mh][1][lane] = g1h + g1l;
    __syncthreads();

    if (wid < 4){
      f32x4 sum = part[0][rmh][rgate][lane] + part[1][rmh][rgate][lane]
                + part[2][rmh][rgate][lane] + part[3][rmh][rgate][lane];
      #pragma unroll
      for (int q = 0; q < 4; ++q){
        int m = (rmh<<4) + ((lane>>4)<<2) + q;
        float pre = sum[q] + bb + pix[q];
        gsm[((rgate<<5) + m)*17 + ar] = 1.f / (1.f + expf(-pre));
      }
    }
    __syncthreads();

    {
      float iv = gsm[um*17 + uk];
      float fv = gsm[(32+um)*17 + uk];
      float cv2 = cfl[um][uk];
      float cn = iv * xq1 + fv * cv2;
      cfl[um][uk] = cn;
      ushort hb = f2bf(cn);
      unsigned word = ((unsigned)(t + 2) << 16) | (unsigned)hb;
      __hip_atomic_store(&pub[((size_t)(t+1) << 15) + (bid << 9) + tid], word,
                         __ATOMIC_RELAXED, __HIP_MEMORY_SCOPE_AGENT);
      cst[((size_t)t << 15) + (bid << 9) + tid] = hb;  // untagged copy for gemm256
      if (t == T_DIM-1) hid_final[(um<<10) + nb + uk] = cn;
    }
    __syncthreads();
  }
}

// init: write tagged c_init into pub slot 0 (tag = 1)
__global__ void init_c_kernel(const float* __restrict__ hidden, unsigned* __restrict__ pub){
  int i = blockIdx.x * blockDim.x + threadIdx.x;   // 0..32767
  float v = hidden[i];
  int m = i >> 10, col = i & 1023;
  pub[((col>>4)<<9) + (m<<4) + (col&15)] = (1u << 16) | (unsigned)f2bf(v);
}

// ---------------- fused lse + subtract: two blocks per row ----------------
__global__ __launch_bounds__(256) void subf_kernel(float* __restrict__ logits,
                                                   const float* __restrict__ pmax,
                                                   const float* __restrict__ psum){
  __shared__ float sl;
  size_t row = blockIdx.x >> 1;
  int half = blockIdx.x & 1;
  int tid = threadIdx.x;
  if (tid < 64){
    float m = -1e30f, s = 0.f;
    for (int i = tid; i < 125; i += 64){
      float mi = pmax[row*125 + i], si = psum[row*125 + i];
      float M = fmaxf(m, mi);
      s = s*expf(m - M) + si*expf(mi - M);
      m = M;
    }
    #pragma unroll
    for (int o = 32; o; o >>= 1){
      float m2 = __shfl_xor(m, o), s2 = __shfl_xor(s, o);
      float M = fmaxf(m, m2);
      s = s*expf(m - M) + s2*expf(m2 - M);
      m = M;
    }
    if (tid == 0) sl = m + logf(s);
  }
  __syncthreads();
  float l = sl;
  float4* p4 = (float4*)(logits + row * (size_t)V_DIM);
  int beg = half * 4000, end = beg + 4000;   // 8000 float4 per row, split in two
  for (int i = beg + tid; i < end; i += 256){
    float4 v = p4[i];
    v.x -= l; v.y -= l; v.z -= l; v.w -= l;
    p4[i] = v;
  }
}

// ---------------- launch ----------------
extern "C" void kernel_launch(void* const* d_in, const int* in_sizes, int n_in,
                              void* d_out, int out_size, void* d_ws, size_t ws_size,
                              hipStream_t stream)
{
  const float* input  = (const float*)d_in[0];
  const float* hidden = (const float*)d_in[1];
  const float* w_ic   = (const float*)d_in[2];
  const float* w_ix   = (const float*)d_in[3];
  const float* w_fc   = (const float*)d_in[4];
  const float* w_fx   = (const float*)d_in[5];
  const float* b_i    = (const float*)d_in[6];
  const float* b_f    = (const float*)d_in[7];
  const float* W_out  = (const float*)d_in[8];
  const float* b_out  = (const float*)d_in[9];
  float* out = (float*)d_out;

  char* ws = (char*)d_ws;
  ushort* wout_bf = (ushort*)(ws + 0);          // 0 .. 65,536,000
  ushort* in_hi   = (ushort*)(ws + 65536000);   // 8,388,608 (dead after ixfx gemm)
  ushort* wx      = (ushort*)(ws + 73924608);   // [w_ix; w_fx] plain bf16, 4,194,304
  ushort* wc_hi   = (ushort*)(ws + 90701824);   // split W for recurrence
  ushort* wc_lo   = (ushort*)(ws + 94896128);
  // overlays (regions dead at time of use):
  unsigned* pub   = (unsigned*)(ws + 65536000); // [129][32768] tagged c, 16,908,288 B
  ushort* cstate  = (ushort*)(ws + 82444288);   // [128][32768] bf16; tail 131KB overlaps wc_hi
                                                //   but only written at t>=126 (W-LDS copies done)
  float*  pmax    = (float*)(ws + 94896128);    // [4096][125] over wc_lo (dead post-ran_all)
  float*  psum    = (float*)(ws + 99090432);
  float*  ixfx    = out;                        // [4096][2048] scratch in logits region

  cast_bf16_kernel<<<2048,256,0,stream>>>(W_out, wout_bf, V_DIM*H_DIM/4);
  cast_bf16_kernel<<<1024,256,0,stream>>>(input, in_hi, MROWS*H_DIM/4);
  cast_bf16_kernel<<<256,256,0,stream>>>(w_ix, wx,             H_DIM*H_DIM/4);
  cast_bf16_kernel<<<256,256,0,stream>>>(w_fx, wx+H_DIM*H_DIM, H_DIM*H_DIM/4);
  cast_split_kernel<<<256,256,0,stream>>>(w_ic, wc_hi,             wc_lo,             H_DIM*H_DIM/4);
  cast_split_kernel<<<256,256,0,stream>>>(w_fc, wc_hi+H_DIM*H_DIM, wc_lo+H_DIM*H_DIM, H_DIM*H_DIM/4);

  // ixfx = input @ [w_ix; w_fx]^T (plain bf16) — before pub overlays in_hi/wx
  gemm_bt_plain<<<32*16,256,0,stream>>>(in_hi, wx, ixfx, 2048, H_DIM, 16);

  // clear tags (graph-replay safety), seed slot 0
  hipMemsetAsync(pub, 0, (size_t)129 * PUBSTEP * 4, stream);
  init_c_kernel<<<128,256,0,stream>>>(hidden, pub);

  ran_all<<<NBLK,512,0,stream>>>(pub, cstate, hidden, wc_hi, wc_lo, b_i, b_f,
                                 ixfx, input, out + (size_t)MROWS*V_DIM);

  // depth-2 pipelined 256^2 logits GEMM + fused LSE partials (reads cstate directly)
  gemm256<<<2000,512,0,stream>>>(cstate, wout_bf, out, b_out, pmax, psum);
  subf_kernel<<<2*MROWS,256,0,stream>>>(out, pmax, psum);
}

// Round 16
// 1862.717 us; speedup vs baseline: 1.0608x; 1.0026x over previous
//
#include <hip/hip_runtime.h>

typedef __attribute__((ext_vector_type(4))) float f32x4;
typedef __attribute__((ext_vector_type(8))) short bf16x8;
typedef __attribute__((ext_vector_type(4))) unsigned u32x4;

#define T_DIM 128
#define B_DIM 32
#define H_DIM 1024
#define V_DIM 32000
#define MROWS 4096    // T*B
#define NBLK 64       // persistent recurrence blocks
#define PUBSTEP 32768 // dwords per slot in tagged pub buffer
#define WSTRIDE 1028  // LDS W row stride (ushorts): bank step 2 -> conflict-free
#define GBK 32        // gemm256 K-tile

__device__ __forceinline__ ushort f2bf(float f){
  union { float f; unsigned u; } x; x.f = f;
  unsigned u = x.u;
  unsigned r = (u + 0x7fffu + ((u >> 16) & 1u)) >> 16;
  return (ushort)r;
}
__device__ __forceinline__ float bf2f(ushort h){
  union { unsigned u; float f; } x; x.u = ((unsigned)h) << 16;
  return x.f;
}

__device__ __forceinline__ void async_copy16(void* lds, const void* g){
  __builtin_amdgcn_global_load_lds((const __attribute__((address_space(1))) void*)g,
                                   (__attribute__((address_space(3))) void*)lds, 16, 0, 0);
}

// ---------------- casts ----------------
__global__ void cast_bf16_kernel(const float* __restrict__ s, ushort* __restrict__ d, int n4){
  int stride = gridDim.x * blockDim.x;
  for (int i = blockIdx.x*blockDim.x + threadIdx.x; i < n4; i += stride){
    float4 v = ((const float4*)s)[i];
    ushort4 o = make_ushort4(f2bf(v.x), f2bf(v.y), f2bf(v.z), f2bf(v.w));
    ((ushort4*)d)[i] = o;
  }
}

__global__ void cast_split_kernel(const float* __restrict__ s, ushort* __restrict__ dh,
                                  ushort* __restrict__ dl, int n4){
  int stride = gridDim.x * blockDim.x;
  for (int i = blockIdx.x*blockDim.x + threadIdx.x; i < n4; i += stride){
    float4 v = ((const float4*)s)[i];
    ushort4 h = make_ushort4(f2bf(v.x), f2bf(v.y), f2bf(v.z), f2bf(v.w));
    ushort4 l = make_ushort4(f2bf(v.x - bf2f(h.x)), f2bf(v.y - bf2f(h.y)),
                             f2bf(v.z - bf2f(h.z)), f2bf(v.w - bf2f(h.w)));
    ((ushort4*)dh)[i] = h;
    ((ushort4*)dl)[i] = l;
  }
}

// ---------------- ixfx GEMM: 256x256-tile, BK=32, depth-2 counted-vmcnt ----------------
// C[4096][2048] = A[4096][1024] * B[2048][1024]^T. Row-major A and B.
// 128 blocks: tn = bid&7 (one N-col per XCD, B panel L2-resident), tm = bid>>3.
__global__ __launch_bounds__(512) void gemm256_ix(
    const ushort* __restrict__ A, const ushort* __restrict__ B, float* __restrict__ C)
{
  __shared__ ushort lA[4][256*GBK];
  __shared__ ushort lB[4][256*GBK];

  const int K = 1024, N = 2048, NT = 32;
  int tid = threadIdx.x, lane = tid & 63, wid = tid >> 6;
  int wm = wid >> 2, wn = wid & 3;
  int tn = blockIdx.x & 7, tm = blockIdx.x >> 3;
  int row0 = tm << 8, col0 = tn << 8;
  int ar = lane & 15, kg = (lane >> 4) << 3;

  auto STAGE = [&](int slot, int kt){
    int k0 = kt << 5;
    #pragma unroll
    for (int j = 0; j < 2; ++j){
      int u = j*512 + tid;
      int r = u >> 2, p = u & 3;
      int g = p ^ ((r >> 1) & 3);
      const ushort* sA = A + (size_t)(row0 + r)*K + k0 + (g << 3);
      async_copy16(&lA[slot][u<<3], sA);
    }
    #pragma unroll
    for (int j = 0; j < 2; ++j){
      int u = j*512 + tid;
      int r = u >> 2, p = u & 3;
      int g = p ^ ((r >> 1) & 3);
      const ushort* sB = B + (size_t)(col0 + r)*K + k0 + (g << 3);
      async_copy16(&lB[slot][u<<3], sB);
    }
  };

  f32x4 acc[8][4] = {};

  STAGE(0, 0);
  STAGE(1, 1);
  int gk = kg >> 3;
  for (int t = 0; t < NT; ++t){
    if (t + 2 < NT) STAGE((t+2) & 3, t+2);
    if (t + 2 < NT)      asm volatile("s_waitcnt vmcnt(8)" ::: "memory");
    else if (t + 1 < NT) asm volatile("s_waitcnt vmcnt(4)" ::: "memory");
    else                 asm volatile("s_waitcnt vmcnt(0)" ::: "memory");
    __builtin_amdgcn_s_barrier();
    __builtin_amdgcn_sched_barrier(0);
    const ushort* bufA = lA[t & 3];
    const ushort* bufB = lB[t & 3];
    bf16x8 a[8], b[4];
    #pragma unroll
    for (int fr = 0; fr < 8; ++fr){
      int row = wm*128 + fr*16 + ar;
      int phys = gk ^ ((row >> 1) & 3);
      a[fr] = *(const bf16x8*)&bufA[row*GBK + (phys << 3)];
    }
    #pragma unroll
    for (int fc = 0; fc < 4; ++fc){
      int row = wn*64 + fc*16 + ar;
      int phys = gk ^ ((row >> 1) & 3);
      b[fc] = *(const bf16x8*)&bufB[row*GBK + (phys << 3)];
    }
    __builtin_amdgcn_s_setprio(1);
    #pragma unroll
    for (int fr = 0; fr < 8; ++fr)
      #pragma unroll
      for (int fc = 0; fc < 4; ++fc)
        acc[fr][fc] = __builtin_amdgcn_mfma_f32_16x16x32_bf16(a[fr], b[fc], acc[fr][fc], 0, 0, 0);
    __builtin_amdgcn_s_setprio(0);
    __builtin_amdgcn_sched_barrier(0);
  }

  #pragma unroll
  for (int fr = 0; fr < 8; ++fr){
    #pragma unroll
    for (int q = 0; q < 4; ++q){
      int r = row0 + wm*128 + fr*16 + (lane>>4)*4 + q;
      #pragma unroll
      for (int fc = 0; fc < 4; ++fc)
        C[(size_t)r * N + col0 + wn*64 + fc*16 + ar] = acc[fr][fc][q];
    }
  }
}

// ---------------- Vproj: 256x256-tile, BK=32, depth-2 counted-vmcnt (r12-exact) ----------------
// C[4096][32000] = A(cstate chunked)[4096][1024] * B[32000][1024]^T + bias, fused LSE partials.
// A chunked: row r -> t=r>>5, m=r&31; elem addr = t*32768 + (k>>4)*512 + m*16 + (k&15).
// 32 K-tiles in 4 LDS slots; STAGE(t+2) issued BEFORE the vmcnt gate. vmcnt(8) drains
// tile t's 4 oldest loads. Granule swizzle phys = conc ^ ((row>>1)&3).
__global__ __launch_bounds__(512) void gemm256(
    const ushort* __restrict__ A, const ushort* __restrict__ B,
    float* __restrict__ C, const float* __restrict__ bias,
    float* __restrict__ pmax, float* __restrict__ psum)
{
  __shared__ ushort lA[4][256*GBK];
  __shared__ ushort lB[4][256*GBK];
  __shared__ float redm[2][4][128], reds[2][4][128];

  const int K = 1024, N = V_DIM, NTN = 125, NT = 32;
  int tid = threadIdx.x, lane = tid & 63, wid = tid >> 6;
  int wm = wid >> 2, wn = wid & 3;
  int bid = blockIdx.x;
  int xcd = bid & 7, id = bid >> 3;       // 2000 blocks: 250 per XCD
  int tm = (xcd << 1) | (id & 1);         // 2 M-bands per XCD (A band L2-resident)
  int tn = id >> 1;                       // 125 N-tiles
  int row0 = tm << 8, col0 = tn << 8;
  int ar = lane & 15, kg = (lane >> 4) << 3;

  auto STAGE = [&](int slot, int kt){
    int k0 = kt << 5;
    #pragma unroll
    for (int j = 0; j < 2; ++j){
      int u = j*512 + tid;                 // A 16B unit: 1024 units
      int r = u >> 2, p = u & 3;           // row, physical granule
      int g = p ^ ((r >> 1) & 3);          // conceptual granule
      int rA = row0 + r, k = k0 + (g << 3);
      const ushort* sA = A + ((size_t)(rA>>5)<<15) + ((size_t)(k>>4)<<9) + ((rA&31)<<4) + (k&15);
      async_copy16(&lA[slot][u<<3], sA);
    }
    #pragma unroll
    for (int j = 0; j < 2; ++j){
      int u = j*512 + tid;
      int r = u >> 2, p = u & 3;
      int g = p ^ ((r >> 1) & 3);
      const ushort* sB = B + (size_t)(col0 + r)*K + k0 + (g << 3);
      async_copy16(&lB[slot][u<<3], sB);
    }
  };

  f32x4 acc[8][4] = {};

  STAGE(0, 0);
  STAGE(1, 1);
  int gk = kg >> 3;                        // conceptual granule of this lane group
  for (int t = 0; t < NT; ++t){
    if (t + 2 < NT) STAGE((t+2) & 3, t+2);
    if (t + 2 < NT)      asm volatile("s_waitcnt vmcnt(8)" ::: "memory");
    else if (t + 1 < NT) asm volatile("s_waitcnt vmcnt(4)" ::: "memory");
    else                 asm volatile("s_waitcnt vmcnt(0)" ::: "memory");
    __builtin_amdgcn_s_barrier();
    __builtin_amdgcn_sched_barrier(0);
    const ushort* bufA = lA[t & 3];
    const ushort* bufB = lB[t & 3];
    bf16x8 a[8], b[4];
    #pragma unroll
    for (int fr = 0; fr < 8; ++fr){
      int row = wm*128 + fr*16 + ar;
      int phys = gk ^ ((row >> 1) & 3);
      a[fr] = *(const bf16x8*)&bufA[row*GBK + (phys << 3)];
    }
    #pragma unroll
    for (int fc = 0; fc < 4; ++fc){
      int row = wn*64 + fc*16 + ar;
      int phys = gk ^ ((row >> 1) & 3);
      b[fc] = *(const bf16x8*)&bufB[row*GBK + (phys << 3)];
    }
    __builtin_amdgcn_s_setprio(1);
    #pragma unroll
    for (int fr = 0; fr < 8; ++fr)
      #pragma unroll
      for (int fc = 0; fc < 4; ++fc)
        acc[fr][fc] = __builtin_amdgcn_mfma_f32_16x16x32_bf16(a[fr], b[fc], acc[fr][fc], 0, 0, 0);
    __builtin_amdgcn_s_setprio(0);
    __builtin_amdgcn_sched_barrier(0);
  }

  // epilogue: bias + C-write + per-(row, tile) LSE partials
  float bb4[4];
  #pragma unroll
  for (int fc = 0; fc < 4; ++fc) bb4[fc] = bias[col0 + wn*64 + fc*16 + ar];
  #pragma unroll
  for (int fr = 0; fr < 8; ++fr){
    #pragma unroll
    for (int q = 0; q < 4; ++q){
      int rl = fr*16 + (lane>>4)*4 + q;
      int r = row0 + wm*128 + rl;
      float vals[4];
      #pragma unroll
      for (int fc = 0; fc < 4; ++fc){
        vals[fc] = acc[fr][fc][q] + bb4[fc];
        C[(size_t)r * N + col0 + wn*64 + fc*16 + ar] = vals[fc];
      }
      float m = fmaxf(fmaxf(vals[0], vals[1]), fmaxf(vals[2], vals[3]));
      #pragma unroll
      for (int o = 1; o < 16; o <<= 1) m = fmaxf(m, __shfl_xor(m, o));
      float s = expf(vals[0]-m) + expf(vals[1]-m) + expf(vals[2]-m) + expf(vals[3]-m);
      #pragma unroll
      for (int o = 1; o < 16; o <<= 1) s += __shfl_xor(s, o);
      if (ar == 0){ redm[wm][wn][rl] = m; reds[wm][wn][rl] = s; }
    }
  }
  __syncthreads();
  if (tid < 256){
    int wm2 = tid >> 7, rl = tid & 127;
    float m0 = redm[wm2][0][rl], m1 = redm[wm2][1][rl];
    float m2 = redm[wm2][2][rl], m3 = redm[wm2][3][rl];
    float M = fmaxf(fmaxf(m0, m1), fmaxf(m2, m3));
    float S = reds[wm2][0][rl]*expf(m0-M) + reds[wm2][1][rl]*expf(m1-M)
            + reds[wm2][2][rl]*expf(m2-M) + reds[wm2][3][rl]*expf(m3-M);
    int r = row0 + wm2*128 + rl;
    pmax[(size_t)r*NTN + tn] = M;
    psum[(size_t)r*NTN + tn] = S;
  }
}

// ---------------- persistent recurrence: tagged dataflow + untagged dual-store ----------------
__global__ __launch_bounds__(512) void ran_all(
    unsigned* __restrict__ pub, ushort* __restrict__ cst,
    const float* __restrict__ hiddenf,
    const ushort* __restrict__ wh, const ushort* __restrict__ wl,
    const float* __restrict__ b_i, const float* __restrict__ b_f,
    const float* __restrict__ ixfx, const float* __restrict__ x_all,
    float* __restrict__ hid_final)
{
  __shared__ ushort lWh[32*WSTRIDE];
  __shared__ ushort lWl[32*WSTRIDE];
  __shared__ f32x4 part[4][2][2][64];   // [kq][mh][gate][lane]
  __shared__ float gsm[2*32*17];
  __shared__ float cfl[32][17];

  int tid = threadIdx.x, lane = tid & 63, wid = tid >> 6;
  int kq = wid & 3, mh = wid >> 2;           // MFMA roles
  int rgate = wid & 1, rmh = (wid >> 1) & 1; // reduce roles (wid<4)
  int bid = blockIdx.x;
  int nb = bid << 4;
  int ar = lane & 15, kg = (lane >> 4) << 3;
  int um = tid >> 4, uk = tid & 15;

  #pragma unroll
  for (int u = 0; u < 8; ++u){
    int unit = u*512 + tid;
    int r = unit >> 7, off = (unit & 127) << 3;
    int g = r >> 4, c = r & 15;
    size_t gsrc = (size_t)((g<<10) + nb + c) * H_DIM + off;
    *(bf16x8*)&lWh[r*WSTRIDE + off] = *(const bf16x8*)&wh[gsrc];
    *(bf16x8*)&lWl[r*WSTRIDE + off] = *(const bf16x8*)&wl[gsrc];
  }
  cfl[um][uk] = hiddenf[(um<<10) + nb + uk];
  float bb = (rgate ? b_f : b_i)[nb + ar];
  const ushort* b0h = &lWh[(     ar)*WSTRIDE + (kq<<8) + kg];
  const ushort* b0l = &lWl[(     ar)*WSTRIDE + (kq<<8) + kg];
  const ushort* b1h = &lWh[(16 + ar)*WSTRIDE + (kq<<8) + kg];
  const ushort* b1l = &lWl[(16 + ar)*WSTRIDE + (kq<<8) + kg];
  int abase = (kq<<13) + ((kg>>4)<<9) + (((mh<<4) + ar)<<4) + (kg & 8);
  __syncthreads();

  for (int t = 0; t < T_DIM; ++t){
    float xq1 = x_all[((size_t)t<<15) + (um<<10) + nb + uk];
    float pix[4];
    if (wid < 4){
      const float* ix_t = ixfx + ((size_t)t<<16);
      #pragma unroll
      for (int q = 0; q < 4; ++q){
        int m = (rmh<<4) + ((lane>>4)<<2) + q;
        pix[q] = ix_t[m*2048 + (rgate<<10) + nb + ar];
      }
    }

    const unsigned* ps = pub + ((size_t)t << 15) + abase;
    unsigned expt = (unsigned)(t + 1) << 16;
    u32x4 w0[8], w1[8];
    int tries = 0;
    while (1){
      #pragma unroll
      for (int f = 0; f < 8; ++f){
        const unsigned* p = ps + (f << 10);
        asm volatile("global_load_dwordx4 %0, %2, off sc0 sc1\n\t"
                     "global_load_dwordx4 %1, %2, off offset:16 sc0 sc1"
                     : "=&v"(w0[f]), "=&v"(w1[f]) : "v"(p));
      }
      asm volatile("s_waitcnt vmcnt(0)" ::: "memory");
      __builtin_amdgcn_sched_barrier(0);
      unsigned bad = 0;
      #pragma unroll
      for (int f = 0; f < 8; ++f){
        bad |= (w0[f][0]^expt)|(w0[f][1]^expt)|(w0[f][2]^expt)|(w0[f][3]^expt)
             | (w1[f][0]^expt)|(w1[f][1]^expt)|(w1[f][2]^expt)|(w1[f][3]^expt);
      }
      if (__ballot((bad & 0xFFFF0000u) != 0) == 0ull) break;
      if (++tries > (1<<15)) break;   // bounded: fail fast, not hang
    }

    f32x4 g0h = {}, g0l = {}, g1h = {}, g1l = {};
    #pragma unroll
    for (int f = 0; f < 8; ++f){
      union { unsigned u[4]; bf16x8 v; } cv;
      cv.u[0] = (w0[f][0] & 0xFFFFu) | (w0[f][1] << 16);
      cv.u[1] = (w0[f][2] & 0xFFFFu) | (w0[f][3] << 16);
      cv.u[2] = (w1[f][0] & 0xFFFFu) | (w1[f][1] << 16);
      cv.u[3] = (w1[f][2] & 0xFFFFu) | (w1[f][3] << 16);
      int ob = f << 5;
      bf16x8 v0h = *(const bf16x8*)&b0h[ob];
      bf16x8 v0l = *(const bf16x8*)&b0l[ob];
      bf16x8 v1h = *(const bf16x8*)&b1h[ob];
      bf16x8 v1l = *(const bf16x8*)&b1l[ob];
      g0h = __builtin_amdgcn_mfma_f32_16x16x32_bf16(cv.v, v0h, g0h, 0, 0, 0);
      g0l = __builtin_amdgcn_mfma_f32_16x16x32_bf16(cv.v, v0l, g0l, 0, 0, 0);
      g1h = __builtin_amdgcn_mfma_f32_16x16x32_bf16(cv.v, v1h, g1h, 0, 0, 0);
      g1l = __builtin_amdgcn_mfma_f32_16x16x32_bf16(cv.v, v1l, g1l, 0, 0, 0);
    }
    part[kq][mh][0][lane] = g0h + g0l;
    part[kq][mh][1][lane] = g1h + g1l;
    __syncthreads();

    if (wid < 4){
      f32x4 sum = part[0][rmh][rgate][lane] + part[1][rmh][rgate][lane]
                + part[2][rmh][rgate][lane] + part[3][rmh][rgate][lane];
      #pragma unroll
      for (int q = 0; q < 4; ++q){
        int m = (rmh<<4) + ((lane>>4)<<2) + q;
        float pre = sum[q] + bb + pix[q];
        gsm[((rgate<<5) + m)*17 + ar] = 1.f / (1.f + expf(-pre));
      }
    }
    __syncthreads();

    {
      float iv = gsm[um*17 + uk];
      float fv = gsm[(32+um)*17 + uk];
      float cv2 = cfl[um][uk];
      float cn = iv * xq1 + fv * cv2;
      cfl[um][uk] = cn;
      ushort hb = f2bf(cn);
      unsigned word = ((unsigned)(t + 2) << 16) | (unsigned)hb;
      __hip_atomic_store(&pub[((size_t)(t+1) << 15) + (bid << 9) + tid], word,
                         __ATOMIC_RELAXED, __HIP_MEMORY_SCOPE_AGENT);
      cst[((size_t)t << 15) + (bid << 9) + tid] = hb;  // untagged copy for gemm256
      if (t == T_DIM-1) hid_final[(um<<10) + nb + uk] = cn;
    }
    __syncthreads();
  }
}

// init: write tagged c_init into pub slot 0 (tag = 1)
__global__ void init_c_kernel(const float* __restrict__ hidden, unsigned* __restrict__ pub){
  int i = blockIdx.x * blockDim.x + threadIdx.x;   // 0..32767
  float v = hidden[i];
  int m = i >> 10, col = i & 1023;
  pub[((col>>4)<<9) + (m<<4) + (col&15)] = (1u << 16) | (unsigned)f2bf(v);
}

// ---------------- fused lse + subtract: two blocks per row ----------------
__global__ __launch_bounds__(256) void subf_kernel(float* __restrict__ logits,
                                                   const float* __restrict__ pmax,
                                                   const float* __restrict__ psum){
  __shared__ float sl;
  size_t row = blockIdx.x >> 1;
  int half = blockIdx.x & 1;
  int tid = threadIdx.x;
  if (tid < 64){
    float m = -1e30f, s = 0.f;
    for (int i = tid; i < 125; i += 64){
      float mi = pmax[row*125 + i], si = psum[row*125 + i];
      float M = fmaxf(m, mi);
      s = s*expf(m - M) + si*expf(mi - M);
      m = M;
    }
    #pragma unroll
    for (int o = 32; o; o >>= 1){
      float m2 = __shfl_xor(m, o), s2 = __shfl_xor(s, o);
      float M = fmaxf(m, m2);
      s = s*expf(m - M) + s2*expf(m2 - M);
      m = M;
    }
    if (tid == 0) sl = m + logf(s);
  }
  __syncthreads();
  float l = sl;
  float4* p4 = (float4*)(logits + row * (size_t)V_DIM);
  int beg = half * 4000, end = beg + 4000;   // 8000 float4 per row, split in two
  for (int i = beg + tid; i < end; i += 256){
    float4 v = p4[i];
    v.x -= l; v.y -= l; v.z -= l; v.w -= l;
    p4[i] = v;
  }
}

// ---------------- launch ----------------
extern "C" void kernel_launch(void* const* d_in, const int* in_sizes, int n_in,
                              void* d_out, int out_size, void* d_ws, size_t ws_size,
                              hipStream_t stream)
{
  const float* input  = (const float*)d_in[0];
  const float* hidden = (const float*)d_in[1];
  const float* w_ic   = (const float*)d_in[2];
  const float* w_ix   = (const float*)d_in[3];
  const float* w_fc   = (const float*)d_in[4];
  const float* w_fx   = (const float*)d_in[5];
  const float* b_i    = (const float*)d_in[6];
  const float* b_f    = (const float*)d_in[7];
  const float* W_out  = (const float*)d_in[8];
  const float* b_out  = (const float*)d_in[9];
  float* out = (float*)d_out;

  char* ws = (char*)d_ws;
  ushort* wout_bf = (ushort*)(ws + 0);          // 0 .. 65,536,000
  ushort* in_hi   = (ushort*)(ws + 65536000);   // 8,388,608 (dead after ixfx gemm)
  ushort* wx      = (ushort*)(ws + 73924608);   // [w_ix; w_fx] plain bf16, 4,194,304
  ushort* wc_hi   = (ushort*)(ws + 90701824);   // split W for recurrence
  ushort* wc_lo   = (ushort*)(ws + 94896128);
  // overlays (regions dead at time of use):
  unsigned* pub   = (unsigned*)(ws + 65536000); // [129][32768] tagged c, 16,908,288 B
  ushort* cstate  = (ushort*)(ws + 82444288);   // [128][32768] bf16; tail 131KB overlaps wc_hi
                                                //   but only written at t>=126 (W-LDS copies done)
  float*  pmax    = (float*)(ws + 94896128);    // [4096][125] over wc_lo (dead post-ran_all)
  float*  psum    = (float*)(ws + 99090432);
  float*  ixfx    = out;                        // [4096][2048] scratch in logits region

  cast_bf16_kernel<<<2048,256,0,stream>>>(W_out, wout_bf, V_DIM*H_DIM/4);
  cast_bf16_kernel<<<1024,256,0,stream>>>(input, in_hi, MROWS*H_DIM/4);
  cast_bf16_kernel<<<256,256,0,stream>>>(w_ix, wx,             H_DIM*H_DIM/4);
  cast_bf16_kernel<<<256,256,0,stream>>>(w_fx, wx+H_DIM*H_DIM, H_DIM*H_DIM/4);
  cast_split_kernel<<<256,256,0,stream>>>(w_ic, wc_hi,             wc_lo,             H_DIM*H_DIM/4);
  cast_split_kernel<<<256,256,0,stream>>>(w_fc, wc_hi+H_DIM*H_DIM, wc_lo+H_DIM*H_DIM, H_DIM*H_DIM/4);

  // ixfx = input @ [w_ix; w_fx]^T (plain bf16, 256^2-tile) — before pub overlays in_hi/wx
  gemm256_ix<<<128,512,0,stream>>>(in_hi, wx, ixfx);

  // clear tags (graph-replay safety), seed slot 0
  hipMemsetAsync(pub, 0, (size_t)129 * PUBSTEP * 4, stream);
  init_c_kernel<<<128,256,0,stream>>>(hidden, pub);

  ran_all<<<NBLK,512,0,stream>>>(pub, cstate, hidden, wc_hi, wc_lo, b_i, b_f,
                                 ixfx, input, out + (size_t)MROWS*V_DIM);

  // depth-2 pipelined 256^2 logits GEMM + fused LSE partials (reads cstate directly)
  gemm256<<<2000,512,0,stream>>>(cstate, wout_bf, out, b_out, pmax, psum);
  subf_kernel<<<2*MROWS,256,0,stream>>>(out, pmax, psum);
}